// Round 4
// baseline (626.515 us; speedup 1.0000x reference)
//
#include <hip/hip_runtime.h>
#include <math.h>

#define DMODEL 1024
#define SEQ    2048
#define NELEM  4194304   // B*S*d
#define N4     (NELEM / 4)

typedef __attribute__((ext_vector_type(8))) short short8;    // 8 bf16 (4 VGPRs)
typedef __attribute__((ext_vector_type(4))) short short4v;   // 4 bf16 (2 VGPRs)
typedef __attribute__((ext_vector_type(4))) float f32x4;     // C/D frag

#define EXP2(x) exp2f(x)

// ---------- numeric helpers (bit-exact vs numpy reference) ----------
__device__ __forceinline__ float fq(float x, float m) {
    float t = x / m * 128.0f;      // correctly-rounded div, exact *128
    float r = rintf(t);            // half-even == np.round
    float q = r * 0.0078125f * m;
    return (m > 0.0f) ? q : x;
}
__device__ __forceinline__ unsigned short f2bf(float f) {   // RNE float->bf16 bits
    unsigned int u = __float_as_uint(f);
    u += 0x7FFFu + ((u >> 16) & 1u);
    return (unsigned short)(u >> 16);
}
__device__ __forceinline__ float bf2f(unsigned short h) {
    return __uint_as_float(((unsigned int)h) << 16);
}
// bf16 bits of rintf(x/m*128): integer in [-128,128] -> exact (truncate works)
__device__ __forceinline__ unsigned short qint(float x, float m) {
    float i = rintf(x / m * 128.0f);
    return (unsigned short)(__float_as_uint(i) >> 16);
}

__device__ __forceinline__ void block_max_atomic(float v, float* red, unsigned int* slot) {
    const int t = threadIdx.x;
    red[t] = v;
    __syncthreads();
    #pragma unroll
    for (int s = 128; s > 0; s >>= 1) {
        if (t < s) red[t] = fmaxf(red[t], red[t + s]);
        __syncthreads();
    }
    if (t == 0) atomicMax(slot, __float_as_uint(red[0]));   // bits monotone for >=0
}

// ---------- elementwise kernels ----------
__global__ __launch_bounds__(256) void absmax_kernel(const float* __restrict__ x, int n4,
                                                     unsigned int* __restrict__ slot) {
    __shared__ float red[256];
    float m = 0.0f;
    const float4* x4 = (const float4*)x;
    for (int i = blockIdx.x * 256 + threadIdx.x; i < n4; i += gridDim.x * 256) {
        float4 v = x4[i];
        m = fmaxf(m, fmaxf(fmaxf(fabsf(v.x), fabsf(v.y)), fmaxf(fabsf(v.z), fabsf(v.w))));
    }
    block_max_atomic(m, red, slot);
}

__global__ __launch_bounds__(256) void quant_int_kernel(const float* __restrict__ src,
                                                        unsigned short* __restrict__ dst,
                                                        const unsigned int* __restrict__ slot,
                                                        int n4) {
    const float m = __uint_as_float(*slot);
    const float4* s4 = (const float4*)src;
    for (int i = blockIdx.x * 256 + threadIdx.x; i < n4; i += gridDim.x * 256) {
        float4 v = s4[i];
        ushort4 o;
        o.x = qint(v.x, m); o.y = qint(v.y, m); o.z = qint(v.z, m); o.w = qint(v.w, m);
        ((ushort4*)dst)[i] = o;
    }
}

__global__ __launch_bounds__(256) void quant_out_kernel(float* __restrict__ Y,
                                                        const unsigned int* __restrict__ slot,
                                                        int n4) {
    const float m = __uint_as_float(*slot);
    float4* y4 = (float4*)Y;
    for (int i = blockIdx.x * 256 + threadIdx.x; i < n4; i += gridDim.x * 256) {
        float4 v = y4[i];
        v.x = fq(v.x, m); v.y = fq(v.y, m); v.z = fq(v.z, m); v.w = fq(v.w, m);
        y4[i] = v;
    }
}

// Split 4 weight matrices into bf16 hi+lo (W ~= hi+lo, residual ~2^-18 rel)
__global__ __launch_bounds__(256) void wsplit_kernel(
    const float* __restrict__ W0, const float* __restrict__ W1,
    const float* __restrict__ W2, const float* __restrict__ W3,
    unsigned short* __restrict__ H0, unsigned short* __restrict__ L0,
    unsigned short* __restrict__ H1, unsigned short* __restrict__ L1,
    unsigned short* __restrict__ H2, unsigned short* __restrict__ L2,
    unsigned short* __restrict__ H3, unsigned short* __restrict__ L3) {
    const int z = blockIdx.y;
    const float* W = (z == 0) ? W0 : (z == 1) ? W1 : (z == 2) ? W2 : W3;
    unsigned short* H = (z == 0) ? H0 : (z == 1) ? H1 : (z == 2) ? H2 : H3;
    unsigned short* L = (z == 0) ? L0 : (z == 1) ? L1 : (z == 2) ? L2 : L3;
    const int i = blockIdx.x * 256 + threadIdx.x;   // grid.x*256 == 1024*1024/4
    float4 w = ((const float4*)W)[i];
    ushort4 h, l;
    h.x = f2bf(w.x); l.x = f2bf(w.x - bf2f(h.x));
    h.y = f2bf(w.y); l.y = f2bf(w.y - bf2f(h.y));
    h.z = f2bf(w.z); l.z = f2bf(w.z - bf2f(h.z));
    h.w = f2bf(w.w); l.w = f2bf(w.w - bf2f(h.w));
    ((ushort4*)H)[i] = h;
    ((ushort4*)L)[i] = l;
}

// V: [b][s][1024] fp32 raw -> Vti [bh][64 d][2048 s] bf16-int (transposed for PV A-frags)
__global__ __launch_bounds__(256) void vtrans_quant(const float* __restrict__ Vraw,
                                                    unsigned short* __restrict__ Vti,
                                                    const unsigned int* __restrict__ slot) {
    __shared__ float tile[64][65];
    const float mv = __uint_as_float(*slot);
    const int t = threadIdx.x;
    const int s0 = blockIdx.x << 6;
    const int bh = blockIdx.y;
    const int b = bh >> 4, h = bh & 15;
    const int rr = t >> 4;            // 0..15
    const int cc = (t & 15) << 2;     // 0..60
    #pragma unroll
    for (int rep = 0; rep < 4; rep++) {
        int srow = rep * 16 + rr;
        float4 v = *(const float4*)&Vraw[(size_t)b * SEQ * DMODEL + (size_t)(s0 + srow) * DMODEL + h * 64 + cc];
        tile[srow][cc + 0] = v.x; tile[srow][cc + 1] = v.y;
        tile[srow][cc + 2] = v.z; tile[srow][cc + 3] = v.w;
    }
    __syncthreads();
    #pragma unroll
    for (int rep = 0; rep < 4; rep++) {
        int drow = rep * 16 + rr;
        ushort4 o;
        o.x = qint(tile[cc + 0][drow], mv);
        o.y = qint(tile[cc + 1][drow], mv);
        o.z = qint(tile[cc + 2][drow], mv);
        o.w = qint(tile[cc + 3][drow], mv);
        *(ushort4*)&Vti[(size_t)bh * 64 * SEQ + (size_t)drow * SEQ + s0 + cc] = o;
    }
}

// ---------- MFMA GEMM: y = (mA/128) * (iA @ (Whi+Wlo)^T) + b ----------
// BM=128, BK=32, BN templated. 4 waves as 2x2. LDS rows stride 40 ushorts.
template<int BN>
__global__ __launch_bounds__(256) void gemm_mfma(
    const unsigned short* __restrict__ Ai, const unsigned int* __restrict__ mSlot,
    const unsigned short* __restrict__ Wh0, const unsigned short* __restrict__ Wl0,
    const float* __restrict__ b0, float* __restrict__ O0, unsigned int* __restrict__ s0,
    const unsigned short* __restrict__ Wh1, const unsigned short* __restrict__ Wl1,
    const float* __restrict__ b1, float* __restrict__ O1, unsigned int* __restrict__ s1) {
    constexpr int NI = BN / 32;
    __shared__ __align__(16) unsigned short As[128 * 40];
    __shared__ __align__(16) unsigned short Bh[BN * 40];
    __shared__ __align__(16) unsigned short Bl[BN * 40];
    __shared__ float red[256];

    const int z = blockIdx.z;
    const unsigned short* Wh = z ? Wh1 : Wh0;
    const unsigned short* Wl = z ? Wl1 : Wl0;
    const float* bias = z ? b1 : b0;
    float* O = z ? O1 : O0;
    unsigned int* slotOut = z ? s1 : s0;

    const float mA = __uint_as_float(*mSlot);
    const int t = threadIdx.x;
    const int lane = t & 63, w = t >> 6;
    const int ml = lane & 15, qd = lane >> 4;
    const int wm = w & 1, wn = w >> 1;
    const int m0 = blockIdx.y << 7;
    const int n0 = blockIdx.x * BN;

    f32x4 acc[4][NI];
    #pragma unroll
    for (int mi = 0; mi < 4; mi++)
        #pragma unroll
        for (int ni = 0; ni < NI; ni++) acc[mi][ni] = (f32x4){0.f, 0.f, 0.f, 0.f};

    for (int k0 = 0; k0 < DMODEL; k0 += 32) {
        __syncthreads();
        #pragma unroll
        for (int c = t; c < 512; c += 256) {
            int r = c >> 2, hh = c & 3;
            *(short8*)&As[r * 40 + hh * 8] = *(const short8*)&Ai[(m0 + r) * DMODEL + k0 + hh * 8];
        }
        #pragma unroll
        for (int c = t; c < BN * 4; c += 256) {
            int r = c >> 2, hh = c & 3;
            *(short8*)&Bh[r * 40 + hh * 8] = *(const short8*)&Wh[(n0 + r) * DMODEL + k0 + hh * 8];
            *(short8*)&Bl[r * 40 + hh * 8] = *(const short8*)&Wl[(n0 + r) * DMODEL + k0 + hh * 8];
        }
        __syncthreads();

        short8 af[4];
        #pragma unroll
        for (int mi = 0; mi < 4; mi++)
            af[mi] = *(const short8*)&As[(wm * 64 + mi * 16 + ml) * 40 + qd * 8];
        #pragma unroll
        for (int ni = 0; ni < NI; ni++) {
            short8 bh = *(const short8*)&Bh[(wn * (BN / 2) + ni * 16 + ml) * 40 + qd * 8];
            short8 bl = *(const short8*)&Bl[(wn * (BN / 2) + ni * 16 + ml) * 40 + qd * 8];
            #pragma unroll
            for (int mi = 0; mi < 4; mi++) {
                acc[mi][ni] = __builtin_amdgcn_mfma_f32_16x16x32_bf16(af[mi], bh, acc[mi][ni], 0, 0, 0);
                acc[mi][ni] = __builtin_amdgcn_mfma_f32_16x16x32_bf16(af[mi], bl, acc[mi][ni], 0, 0, 0);
            }
        }
    }

    const float s = mA * 0.0078125f;
    float lmax = 0.0f;
    #pragma unroll
    for (int ni = 0; ni < NI; ni++) {
        const int col = n0 + wn * (BN / 2) + ni * 16 + ml;
        const float bc = bias[col];
        #pragma unroll
        for (int mi = 0; mi < 4; mi++) {
            #pragma unroll
            for (int r = 0; r < 4; r++) {
                int row = m0 + wm * 64 + mi * 16 + qd * 4 + r;
                float v = acc[mi][ni][r] * s + bc;
                lmax = fmaxf(lmax, fabsf(v));
                O[row * DMODEL + col] = v;
            }
        }
    }
    block_max_atomic(lmax, red, slotOut);
}

// ---------- MFMA flash attention, transposed (S^T = K Q^T), barrier-free k-loop ----------
// WG = 4 waves; wave w owns q-cols [q0+w*16, q0+w*16+16). K/V A-frags read directly
// from global (L2-resident). S^T C-layout puts all 16 scores of one q-col in-lane ->
// softmax is in-lane; P^T is then ALREADY in B-operand layout for K=16 MFMA
// (B[k=quad*4+j][n=lane&15] == C[row=quad*4+r][col=lane&15]) -> PV needs no shuffles.
__global__ __launch_bounds__(256) void attn_mfma(
    const float* __restrict__ Qraw, const unsigned short* __restrict__ Ki,
    const unsigned short* __restrict__ Vti, const unsigned int* __restrict__ slots,
    float* __restrict__ Out, unsigned int* __restrict__ moSlot) {
    __shared__ float red[256];
    union U8 { short8 v; unsigned short u[8]; };
    union U4 { short4v v; unsigned short u[4]; };

    const int t = threadIdx.x;
    const int lane = t & 63, w = t >> 6;
    const int ml = lane & 15, qd = lane >> 4;
    const int q0 = blockIdx.x << 6;
    const int bh = blockIdx.y;
    const int b = bh >> 4, h = bh & 15;
    const float mq = __uint_as_float(slots[1]);
    const float mk = __uint_as_float(slots[2]);
    const float mv = __uint_as_float(slots[3]);
    // score scale folded with log2(e): p = exp2((t_acc - m_acc)*c2)
    const float c2 = (mq * 0.0078125f) * (mk * 0.0078125f) * 0.125f * 1.4426950408889634f;
    const int baseQ = b * SEQ * DMODEL + h * 64;
    const int qg = q0 + w * 16 + ml;

    // Q B-frags (quantize once from raw): bq[c] holds Q[qg][c*32 + qd*8 + j]
    short8 bq[2];
    {
        const float* src = Qraw + baseQ + qg * DMODEL + qd * 8;
        #pragma unroll
        for (int c = 0; c < 2; c++) {
            float4 v0 = *(const float4*)(src + c * 32);
            float4 v1 = *(const float4*)(src + c * 32 + 4);
            U8 tmp;
            tmp.u[0] = qint(v0.x, mq); tmp.u[1] = qint(v0.y, mq);
            tmp.u[2] = qint(v0.z, mq); tmp.u[3] = qint(v0.w, mq);
            tmp.u[4] = qint(v1.x, mq); tmp.u[5] = qint(v1.y, mq);
            tmp.u[6] = qint(v1.z, mq); tmp.u[7] = qint(v1.w, mq);
            bq[c] = tmp.v;
        }
    }

    f32x4 oacc[4];
    #pragma unroll
    for (int i = 0; i < 4; i++) oacc[i] = (f32x4){0.f, 0.f, 0.f, 0.f};
    float mrun = -INFINITY, lrun = 0.0f;

    const unsigned short* vbase = Vti + (size_t)bh * 64 * SEQ + (size_t)ml * SEQ + qd * 4;

    for (int k0 = 0; k0 < SEQ; k0 += 64) {
        // ---- S^T tile: A=K rows (kk), B=Q. sacc[tau][r] = S^T[k0+tau*16+qd*4+r][qg]
        f32x4 sacc[4];
        const unsigned short* kb = Ki + baseQ + (size_t)(k0 + ml) * DMODEL + qd * 8;
        #pragma unroll
        for (int tau = 0; tau < 4; tau++) {
            short8 a0 = *(const short8*)(kb + (size_t)tau * 16 * DMODEL);
            short8 a1 = *(const short8*)(kb + (size_t)tau * 16 * DMODEL + 32);
            f32x4 z4 = (f32x4){0.f, 0.f, 0.f, 0.f};
            z4 = __builtin_amdgcn_mfma_f32_16x16x32_bf16(a0, bq[0], z4, 0, 0, 0);
            sacc[tau] = __builtin_amdgcn_mfma_f32_16x16x32_bf16(a1, bq[1], sacc[tau] = z4, 0, 0, 0);
        }

        // ---- online softmax: all 16 scores of q-col qg live in this lane
        float tmax = fmaxf(fmaxf(fmaxf(sacc[0][0], sacc[0][1]), fmaxf(sacc[0][2], sacc[0][3])),
                           fmaxf(fmaxf(sacc[1][0], sacc[1][1]), fmaxf(sacc[1][2], sacc[1][3])));
        tmax = fmaxf(tmax, fmaxf(fmaxf(fmaxf(sacc[2][0], sacc[2][1]), fmaxf(sacc[2][2], sacc[2][3])),
                                 fmaxf(fmaxf(sacc[3][0], sacc[3][1]), fmaxf(sacc[3][2], sacc[3][3]))));
        tmax = fmaxf(tmax, __shfl_xor(tmax, 16));
        tmax = fmaxf(tmax, __shfl_xor(tmax, 32));
        const float mnew = fmaxf(mrun, tmax);
        const float alpha = EXP2((mrun - mnew) * c2);
        const float mc = mnew * c2;
        float p[4][4];
        float ls = 0.0f;
        #pragma unroll
        for (int tau = 0; tau < 4; tau++)
            #pragma unroll
            for (int r = 0; r < 4; r++) {
                float pv = EXP2(sacc[tau][r] * c2 - mc);
                p[tau][r] = pv;
                ls += pv;
            }
        ls += __shfl_xor(ls, 16);
        ls += __shfl_xor(ls, 32);
        lrun = lrun * alpha + ls;
        mrun = mnew;

        // ---- split P into bf16 hi/lo: p[tau][0..3] is ALREADY the K=16 B-frag
        short4v phi[4], plo[4];
        #pragma unroll
        for (int tau = 0; tau < 4; tau++) {
            U4 hh, ll;
            #pragma unroll
            for (int r = 0; r < 4; r++) {
                unsigned int u = __float_as_uint(p[tau][r]);
                unsigned int uh = (u + 0x8000u) & 0xFFFF0000u;   // round-to-nearest hi
                hh.u[r] = (unsigned short)(uh >> 16);
                float lf = p[tau][r] - __uint_as_float(uh);      // exact residual
                ll.u[r] = (unsigned short)(__float_as_uint(lf) >> 16);  // trunc lo
            }
            phi[tau] = hh.v;
            plo[tau] = ll.v;
        }

        // ---- rescale O
        #pragma unroll
        for (int i = 0; i < 4; i++) {
            oacc[i][0] *= alpha; oacc[i][1] *= alpha;
            oacc[i][2] *= alpha; oacc[i][3] *= alpha;
        }

        // ---- O^T += V^T P^T via K=16 MFMA (A = V^T 8B frags straight from global)
        const unsigned short* vb = vbase + k0;
        #pragma unroll
        for (int td = 0; td < 4; td++) {
            const unsigned short* vrow = vb + (size_t)td * 16 * SEQ;
            #pragma unroll
            for (int tau = 0; tau < 4; tau++) {
                short4v av = *(const short4v*)(vrow + tau * 16);
                oacc[td] = __builtin_amdgcn_mfma_f32_16x16x16bf16_1k(av, phi[tau], oacc[td], 0, 0, 0);
                oacc[td] = __builtin_amdgcn_mfma_f32_16x16x16bf16_1k(av, plo[tau], oacc[td], 0, 0, 0);
            }
        }
    }

    // ---- epilogue: O[qg][d] = oacc[td][r] * (mv/128) / lrun
    const float inv = (mv * 0.0078125f) / lrun;
    float lmax = 0.0f;
    #pragma unroll
    for (int td = 0; td < 4; td++) {
        float4 o;
        o.x = oacc[td][0] * inv;
        o.y = oacc[td][1] * inv;
        o.z = oacc[td][2] * inv;
        o.w = oacc[td][3] * inv;
        lmax = fmaxf(lmax, fmaxf(fmaxf(fabsf(o.x), fabsf(o.y)), fmaxf(fabsf(o.z), fabsf(o.w))));
        *(float4*)&Out[baseQ + (size_t)qg * DMODEL + td * 16 + qd * 4] = o;
    }
    block_max_atomic(lmax, red, moSlot);
}

// ---------- launcher ----------
extern "C" void kernel_launch(void* const* d_in, const int* in_sizes, int n_in,
                              void* d_out, int out_size, void* d_ws, size_t ws_size,
                              hipStream_t stream) {
    const float* x  = (const float*)d_in[0];
    const float* Wq = (const float*)d_in[1];
    const float* bq = (const float*)d_in[2];
    const float* Wk = (const float*)d_in[3];
    const float* bk = (const float*)d_in[4];
    const float* Wv = (const float*)d_in[5];
    const float* bv = (const float*)d_in[6];
    const float* Wo = (const float*)d_in[7];
    const float* bo = (const float*)d_in[8];
    float* out = (float*)d_out;

    const size_t MB = 1024 * 1024;
    unsigned int* slots = (unsigned int*)d_ws;
    char* p = (char*)d_ws + 256;
    unsigned short* WqH = (unsigned short*)(p + 0 * MB);
    unsigned short* WqL = (unsigned short*)(p + 2 * MB);
    unsigned short* WkH = (unsigned short*)(p + 4 * MB);
    unsigned short* WkL = (unsigned short*)(p + 6 * MB);
    unsigned short* WvH = (unsigned short*)(p + 8 * MB);
    unsigned short* WvL = (unsigned short*)(p + 10 * MB);
    unsigned short* WoH = (unsigned short*)(p + 12 * MB);
    unsigned short* WoL = (unsigned short*)(p + 14 * MB);
    unsigned short* Xi  = (unsigned short*)(p + 16 * MB);  // 8 MB, x as int-bf16
    float* RA  = (float*)(p + 24 * MB);                    // 16 MB: Kraw -> Qraw -> Oi
    float* RB  = (float*)(p + 40 * MB);                    // 16 MB: Vraw -> attn-out raw
    unsigned short* Vti = (unsigned short*)(p + 56 * MB);  // 8 MB, V^T int-bf16
    unsigned short* Ki  = (unsigned short*)(p + 4 * MB);   // 8 MB, overlays Wk/Wv splits (dead)
    unsigned short* Oi  = (unsigned short*)RA;             // 8 MB, overlays Qraw (dead)

    hipMemsetAsync(d_ws, 0, 256, stream);  // zero max slots

    wsplit_kernel<<<dim3(1024, 4), 256, 0, stream>>>(Wq, Wk, Wv, Wo,
        WqH, WqL, WkH, WkL, WvH, WvL, WoH, WoL);
    absmax_kernel<<<1024, 256, 0, stream>>>(x, N4, slots + 0);
    quant_int_kernel<<<1024, 256, 0, stream>>>(x, Xi, slots + 0, N4);

    // K and V projections (z=0: K, z=1: V); raw fp32 out + global max
    gemm_mfma<128><<<dim3(8, 32, 2), 256, 0, stream>>>(Xi, slots + 0,
        WkH, WkL, bk, RA, slots + 2,
        WvH, WvL, bv, RB, slots + 3);
    quant_int_kernel<<<1024, 256, 0, stream>>>(RA, Ki, slots + 2, N4);
    vtrans_quant<<<dim3(32, 32), 256, 0, stream>>>(RB, Vti, slots + 3);

    // Q projection (raw into RA, over dead Kraw)
    gemm_mfma<128><<<dim3(8, 32, 1), 256, 0, stream>>>(Xi, slots + 0,
        WqH, WqL, bq, RA, slots + 1,
        WqH, WqL, bq, RA, slots + 1);

    // attention: raw out into RB (over dead Vraw), slot4 = max|attn out|
    attn_mfma<<<dim3(32, 32), 256, 0, stream>>>(RA, Ki, Vti, slots, RB, slots + 4);
    quant_int_kernel<<<1024, 256, 0, stream>>>(RB, Oi, slots + 4, N4);

    // O projection straight into d_out (raw), then final fake-quant in place
    gemm_mfma<128><<<dim3(8, 32, 1), 256, 0, stream>>>(Oi, slots + 4,
        WoH, WoL, bo, out, slots + 5,
        WoH, WoL, bo, out, slots + 5);
    quant_out_kernel<<<1024, 256, 0, stream>>>(out, slots + 5, N4);
}

// Round 5
// 383.025 us; speedup vs baseline: 1.6357x; 1.6357x over previous
//
#include <hip/hip_runtime.h>
#include <math.h>

#define DMODEL 1024
#define SEQ    2048
#define NELEM  4194304   // B*S*d
#define N4     (NELEM / 4)

typedef __attribute__((ext_vector_type(8))) short short8;    // 8 bf16 (4 VGPRs)
typedef __attribute__((ext_vector_type(4))) short short4v;   // 4 bf16 (2 VGPRs)
typedef __attribute__((ext_vector_type(4))) float f32x4;     // C/D frag

#define EXP2(x) exp2f(x)

// ---------- numeric helpers (bit-exact vs numpy reference) ----------
__device__ __forceinline__ float fq(float x, float m) {
    float t = x / m * 128.0f;      // correctly-rounded div, exact *128
    float r = rintf(t);            // half-even == np.round
    float q = r * 0.0078125f * m;
    return (m > 0.0f) ? q : x;
}
__device__ __forceinline__ unsigned short f2bf(float f) {   // RNE float->bf16 bits
    unsigned int u = __float_as_uint(f);
    u += 0x7FFFu + ((u >> 16) & 1u);
    return (unsigned short)(u >> 16);
}
__device__ __forceinline__ float bf2f(unsigned short h) {
    return __uint_as_float(((unsigned int)h) << 16);
}
// bf16 bits of rintf(x/m*128): integer in [-128,128] -> exact (truncate works)
__device__ __forceinline__ unsigned short qint(float x, float m) {
    float i = rintf(x / m * 128.0f);
    return (unsigned short)(__float_as_uint(i) >> 16);
}

__device__ __forceinline__ void block_max_atomic(float v, float* red, unsigned int* slot) {
    const int t = threadIdx.x;
    red[t] = v;
    __syncthreads();
    #pragma unroll
    for (int s = 128; s > 0; s >>= 1) {
        if (t < s) red[t] = fmaxf(red[t], red[t + s]);
        __syncthreads();
    }
    if (t == 0) atomicMax(slot, __float_as_uint(red[0]));   // bits monotone for >=0
}

// ---------- elementwise kernels ----------
__global__ __launch_bounds__(256) void absmax_kernel(const float* __restrict__ x, int n4,
                                                     unsigned int* __restrict__ slot) {
    __shared__ float red[256];
    float m = 0.0f;
    const float4* x4 = (const float4*)x;
    for (int i = blockIdx.x * 256 + threadIdx.x; i < n4; i += gridDim.x * 256) {
        float4 v = x4[i];
        m = fmaxf(m, fmaxf(fmaxf(fabsf(v.x), fabsf(v.y)), fmaxf(fabsf(v.z), fabsf(v.w))));
    }
    block_max_atomic(m, red, slot);
}

__global__ __launch_bounds__(256) void quant_int_kernel(const float* __restrict__ src,
                                                        unsigned short* __restrict__ dst,
                                                        const unsigned int* __restrict__ slot,
                                                        int n4) {
    const float m = __uint_as_float(*slot);
    const float4* s4 = (const float4*)src;
    for (int i = blockIdx.x * 256 + threadIdx.x; i < n4; i += gridDim.x * 256) {
        float4 v = s4[i];
        ushort4 o;
        o.x = qint(v.x, m); o.y = qint(v.y, m); o.z = qint(v.z, m); o.w = qint(v.w, m);
        ((ushort4*)dst)[i] = o;
    }
}

__global__ __launch_bounds__(256) void quant_out_kernel(float* __restrict__ Y,
                                                        const unsigned int* __restrict__ slot,
                                                        int n4) {
    const float m = __uint_as_float(*slot);
    float4* y4 = (float4*)Y;
    for (int i = blockIdx.x * 256 + threadIdx.x; i < n4; i += gridDim.x * 256) {
        float4 v = y4[i];
        v.x = fq(v.x, m); v.y = fq(v.y, m); v.z = fq(v.z, m); v.w = fq(v.w, m);
        y4[i] = v;
    }
}

// Split 4 weight matrices into bf16 hi+lo (W ~= hi+lo, residual ~2^-18 rel)
__global__ __launch_bounds__(256) void wsplit_kernel(
    const float* __restrict__ W0, const float* __restrict__ W1,
    const float* __restrict__ W2, const float* __restrict__ W3,
    unsigned short* __restrict__ H0, unsigned short* __restrict__ L0,
    unsigned short* __restrict__ H1, unsigned short* __restrict__ L1,
    unsigned short* __restrict__ H2, unsigned short* __restrict__ L2,
    unsigned short* __restrict__ H3, unsigned short* __restrict__ L3) {
    const int z = blockIdx.y;
    const float* W = (z == 0) ? W0 : (z == 1) ? W1 : (z == 2) ? W2 : W3;
    unsigned short* H = (z == 0) ? H0 : (z == 1) ? H1 : (z == 2) ? H2 : H3;
    unsigned short* L = (z == 0) ? L0 : (z == 1) ? L1 : (z == 2) ? L2 : L3;
    const int i = blockIdx.x * 256 + threadIdx.x;   // grid.x*256 == 1024*1024/4
    float4 w = ((const float4*)W)[i];
    ushort4 h, l;
    h.x = f2bf(w.x); l.x = f2bf(w.x - bf2f(h.x));
    h.y = f2bf(w.y); l.y = f2bf(w.y - bf2f(h.y));
    h.z = f2bf(w.z); l.z = f2bf(w.z - bf2f(h.z));
    h.w = f2bf(w.w); l.w = f2bf(w.w - bf2f(h.w));
    ((ushort4*)H)[i] = h;
    ((ushort4*)L)[i] = l;
}

// V: [b][s][1024] fp32 raw -> Vti [bh][64 d][2048 s] bf16-int (transposed for PV A-frags)
__global__ __launch_bounds__(256) void vtrans_quant(const float* __restrict__ Vraw,
                                                    unsigned short* __restrict__ Vti,
                                                    const unsigned int* __restrict__ slot) {
    __shared__ float tile[64][65];
    const float mv = __uint_as_float(*slot);
    const int t = threadIdx.x;
    const int s0 = blockIdx.x << 6;
    const int bh = blockIdx.y;
    const int b = bh >> 4, h = bh & 15;
    const int rr = t >> 4;            // 0..15
    const int cc = (t & 15) << 2;     // 0..60
    #pragma unroll
    for (int rep = 0; rep < 4; rep++) {
        int srow = rep * 16 + rr;
        float4 v = *(const float4*)&Vraw[(size_t)b * SEQ * DMODEL + (size_t)(s0 + srow) * DMODEL + h * 64 + cc];
        tile[srow][cc + 0] = v.x; tile[srow][cc + 1] = v.y;
        tile[srow][cc + 2] = v.z; tile[srow][cc + 3] = v.w;
    }
    __syncthreads();
    #pragma unroll
    for (int rep = 0; rep < 4; rep++) {
        int drow = rep * 16 + rr;
        ushort4 o;
        o.x = qint(tile[cc + 0][drow], mv);
        o.y = qint(tile[cc + 1][drow], mv);
        o.z = qint(tile[cc + 2][drow], mv);
        o.w = qint(tile[cc + 3][drow], mv);
        *(ushort4*)&Vti[(size_t)bh * 64 * SEQ + (size_t)drow * SEQ + s0 + cc] = o;
    }
}

// ---------- MFMA GEMM: y = (mA/128) * (iA @ (Whi+Wlo)^T) + b ----------
// BM=128, BK=32, BN templated. 4 waves as 2x2. LDS rows stride 40 ushorts.
template<int BN>
__global__ __launch_bounds__(256) void gemm_mfma(
    const unsigned short* __restrict__ Ai, const unsigned int* __restrict__ mSlot,
    const unsigned short* __restrict__ Wh0, const unsigned short* __restrict__ Wl0,
    const float* __restrict__ b0, float* __restrict__ O0, unsigned int* __restrict__ s0,
    const unsigned short* __restrict__ Wh1, const unsigned short* __restrict__ Wl1,
    const float* __restrict__ b1, float* __restrict__ O1, unsigned int* __restrict__ s1) {
    constexpr int NI = BN / 32;
    __shared__ __align__(16) unsigned short As[128 * 40];
    __shared__ __align__(16) unsigned short Bh[BN * 40];
    __shared__ __align__(16) unsigned short Bl[BN * 40];
    __shared__ float red[256];

    const int z = blockIdx.z;
    const unsigned short* Wh = z ? Wh1 : Wh0;
    const unsigned short* Wl = z ? Wl1 : Wl0;
    const float* bias = z ? b1 : b0;
    float* O = z ? O1 : O0;
    unsigned int* slotOut = z ? s1 : s0;

    const float mA = __uint_as_float(*mSlot);
    const int t = threadIdx.x;
    const int lane = t & 63, w = t >> 6;
    const int ml = lane & 15, qd = lane >> 4;
    const int wm = w & 1, wn = w >> 1;
    const int m0 = blockIdx.y << 7;
    const int n0 = blockIdx.x * BN;

    f32x4 acc[4][NI];
    #pragma unroll
    for (int mi = 0; mi < 4; mi++)
        #pragma unroll
        for (int ni = 0; ni < NI; ni++) acc[mi][ni] = (f32x4){0.f, 0.f, 0.f, 0.f};

    for (int k0 = 0; k0 < DMODEL; k0 += 32) {
        __syncthreads();
        #pragma unroll
        for (int c = t; c < 512; c += 256) {
            int r = c >> 2, hh = c & 3;
            *(short8*)&As[r * 40 + hh * 8] = *(const short8*)&Ai[(m0 + r) * DMODEL + k0 + hh * 8];
        }
        #pragma unroll
        for (int c = t; c < BN * 4; c += 256) {
            int r = c >> 2, hh = c & 3;
            *(short8*)&Bh[r * 40 + hh * 8] = *(const short8*)&Wh[(n0 + r) * DMODEL + k0 + hh * 8];
            *(short8*)&Bl[r * 40 + hh * 8] = *(const short8*)&Wl[(n0 + r) * DMODEL + k0 + hh * 8];
        }
        __syncthreads();

        short8 af[4];
        #pragma unroll
        for (int mi = 0; mi < 4; mi++)
            af[mi] = *(const short8*)&As[(wm * 64 + mi * 16 + ml) * 40 + qd * 8];
        #pragma unroll
        for (int ni = 0; ni < NI; ni++) {
            short8 bh = *(const short8*)&Bh[(wn * (BN / 2) + ni * 16 + ml) * 40 + qd * 8];
            short8 bl = *(const short8*)&Bl[(wn * (BN / 2) + ni * 16 + ml) * 40 + qd * 8];
            #pragma unroll
            for (int mi = 0; mi < 4; mi++) {
                acc[mi][ni] = __builtin_amdgcn_mfma_f32_16x16x32_bf16(af[mi], bh, acc[mi][ni], 0, 0, 0);
                acc[mi][ni] = __builtin_amdgcn_mfma_f32_16x16x32_bf16(af[mi], bl, acc[mi][ni], 0, 0, 0);
            }
        }
    }

    const float s = mA * 0.0078125f;
    float lmax = 0.0f;
    #pragma unroll
    for (int ni = 0; ni < NI; ni++) {
        const int col = n0 + wn * (BN / 2) + ni * 16 + ml;
        const float bc = bias[col];
        #pragma unroll
        for (int mi = 0; mi < 4; mi++) {
            #pragma unroll
            for (int r = 0; r < 4; r++) {
                int row = m0 + wm * 64 + mi * 16 + qd * 4 + r;
                float v = acc[mi][ni][r] * s + bc;
                lmax = fmaxf(lmax, fabsf(v));
                O[row * DMODEL + col] = v;
            }
        }
    }
    block_max_atomic(lmax, red, slotOut);
}

// ---------- MFMA flash attention: transposed S^T = K Q^T + LDS-staged K/V ----------
// WG = 4 waves; wave w owns q-cols [q0+w*16, q0+w*16+16). K/V tiles staged
// cooperatively (coalesced) into LDS each k-iter; A-frags via ds_read.
// S^T C-layout puts all 16 scores of one q-col in-lane -> in-lane softmax;
// P^T is ALREADY the K=16 MFMA B-operand layout -> PV needs no cross-lane ops.
__global__ __launch_bounds__(256) void attn_mfma(
    const float* __restrict__ Qraw, const unsigned short* __restrict__ Ki,
    const unsigned short* __restrict__ Vti, const unsigned int* __restrict__ slots,
    float* __restrict__ Out, unsigned int* __restrict__ moSlot) {
    __shared__ __align__(16) unsigned short Ks[64 * 72];   // [k][d], 9 KB
    __shared__ __align__(16) unsigned short Vt[64 * 72];   // [d][k], 9 KB
    __shared__ float red[256];
    union U8 { short8 v; unsigned short u[8]; };
    union U4 { short4v v; unsigned short u[4]; };

    const int t = threadIdx.x;
    const int lane = t & 63, w = t >> 6;
    const int ml = lane & 15, qd = lane >> 4;
    const int q0 = blockIdx.x << 6;
    const int bh = blockIdx.y;
    const int b = bh >> 4, h = bh & 15;
    const float mq = __uint_as_float(slots[1]);
    const float mk = __uint_as_float(slots[2]);
    const float mv = __uint_as_float(slots[3]);
    // score scale folded with log2(e): p = exp2((s_acc - m_acc)*c2)
    const float c2 = (mq * 0.0078125f) * (mk * 0.0078125f) * 0.125f * 1.4426950408889634f;
    const int baseQ = b * SEQ * DMODEL + h * 64;
    const int qg = q0 + w * 16 + ml;

    // Q B-frags (quantize once from raw): bq[c] holds Q[qg][c*32 + qd*8 + j]
    short8 bq[2];
    {
        const float* src = Qraw + baseQ + qg * DMODEL + qd * 8;
        #pragma unroll
        for (int c = 0; c < 2; c++) {
            float4 v0 = *(const float4*)(src + c * 32);
            float4 v1 = *(const float4*)(src + c * 32 + 4);
            U8 tmp;
            tmp.u[0] = qint(v0.x, mq); tmp.u[1] = qint(v0.y, mq);
            tmp.u[2] = qint(v0.z, mq); tmp.u[3] = qint(v0.w, mq);
            tmp.u[4] = qint(v1.x, mq); tmp.u[5] = qint(v1.y, mq);
            tmp.u[6] = qint(v1.z, mq); tmp.u[7] = qint(v1.w, mq);
            bq[c] = tmp.v;
        }
    }

    f32x4 oacc[4];
    #pragma unroll
    for (int i = 0; i < 4; i++) oacc[i] = (f32x4){0.f, 0.f, 0.f, 0.f};
    float mrun = -INFINITY, lrun = 0.0f;

    // cooperative staging indices: thread t loads row r = t>>2, 32B segment (t&3)
    const int sr = t >> 2;
    const int sc = (t & 3) << 4;            // ushort offset 0,16,32,48
    const unsigned short* kstage = Ki + baseQ + (size_t)sr * DMODEL + sc;
    const unsigned short* vstage = Vti + (size_t)bh * 64 * SEQ + (size_t)sr * SEQ + sc;

    for (int k0 = 0; k0 < SEQ; k0 += 64) {
        __syncthreads();   // protect LDS reuse from previous iteration
        *(short8*)&Ks[sr * 72 + sc]     = *(const short8*)(kstage + (size_t)k0 * DMODEL);
        *(short8*)&Ks[sr * 72 + sc + 8] = *(const short8*)(kstage + (size_t)k0 * DMODEL + 8);
        *(short8*)&Vt[sr * 72 + sc]     = *(const short8*)(vstage + k0);
        *(short8*)&Vt[sr * 72 + sc + 8] = *(const short8*)(vstage + k0 + 8);
        __syncthreads();

        // ---- S^T tile: A=K rows (kk), B=Q. sacc[tau][r] = S^T[k0+tau*16+qd*4+r][qg]
        f32x4 sacc[4];
        #pragma unroll
        for (int tau = 0; tau < 4; tau++) {
            short8 a0 = *(const short8*)&Ks[(tau * 16 + ml) * 72 + qd * 8];
            short8 a1 = *(const short8*)&Ks[(tau * 16 + ml) * 72 + 32 + qd * 8];
            f32x4 z4 = (f32x4){0.f, 0.f, 0.f, 0.f};
            z4 = __builtin_amdgcn_mfma_f32_16x16x32_bf16(a0, bq[0], z4, 0, 0, 0);
            sacc[tau] = __builtin_amdgcn_mfma_f32_16x16x32_bf16(a1, bq[1], z4, 0, 0, 0);
        }

        // ---- online softmax: all 16 scores of q-col qg live in this lane
        float tmax = fmaxf(fmaxf(fmaxf(sacc[0][0], sacc[0][1]), fmaxf(sacc[0][2], sacc[0][3])),
                           fmaxf(fmaxf(sacc[1][0], sacc[1][1]), fmaxf(sacc[1][2], sacc[1][3])));
        tmax = fmaxf(tmax, fmaxf(fmaxf(fmaxf(sacc[2][0], sacc[2][1]), fmaxf(sacc[2][2], sacc[2][3])),
                                 fmaxf(fmaxf(sacc[3][0], sacc[3][1]), fmaxf(sacc[3][2], sacc[3][3]))));
        tmax = fmaxf(tmax, __shfl_xor(tmax, 16));
        tmax = fmaxf(tmax, __shfl_xor(tmax, 32));
        const float mnew = fmaxf(mrun, tmax);
        const float alpha = EXP2((mrun - mnew) * c2);
        const float mc = mnew * c2;
        float p[4][4];
        float ls = 0.0f;
        #pragma unroll
        for (int tau = 0; tau < 4; tau++)
            #pragma unroll
            for (int r = 0; r < 4; r++) {
                float pv = EXP2(sacc[tau][r] * c2 - mc);
                p[tau][r] = pv;
                ls += pv;
            }
        ls += __shfl_xor(ls, 16);
        ls += __shfl_xor(ls, 32);
        lrun = lrun * alpha + ls;
        mrun = mnew;

        // ---- split P into bf16 hi/lo: p[tau][0..3] is ALREADY the K=16 B-frag
        short4v phi[4], plo[4];
        #pragma unroll
        for (int tau = 0; tau < 4; tau++) {
            U4 hh, ll;
            #pragma unroll
            for (int r = 0; r < 4; r++) {
                unsigned int u = __float_as_uint(p[tau][r]);
                unsigned int uh = (u + 0x8000u) & 0xFFFF0000u;   // round-to-nearest hi
                hh.u[r] = (unsigned short)(uh >> 16);
                float lf = p[tau][r] - __uint_as_float(uh);      // exact residual
                ll.u[r] = (unsigned short)(__float_as_uint(lf) >> 16);  // trunc lo
            }
            phi[tau] = hh.v;
            plo[tau] = ll.v;
        }

        // ---- rescale O
        #pragma unroll
        for (int i = 0; i < 4; i++) {
            oacc[i][0] *= alpha; oacc[i][1] *= alpha;
            oacc[i][2] *= alpha; oacc[i][3] *= alpha;
        }

        // ---- O^T += V^T P^T via K=16 MFMA (A = V^T 8B frags from LDS)
        #pragma unroll
        for (int td = 0; td < 4; td++) {
            #pragma unroll
            for (int tau = 0; tau < 4; tau++) {
                short4v av = *(const short4v*)&Vt[(td * 16 + ml) * 72 + tau * 16 + qd * 4];
                oacc[td] = __builtin_amdgcn_mfma_f32_16x16x16bf16_1k(av, phi[tau], oacc[td], 0, 0, 0);
                oacc[td] = __builtin_amdgcn_mfma_f32_16x16x16bf16_1k(av, plo[tau], oacc[td], 0, 0, 0);
            }
        }
    }

    // ---- epilogue: O[qg][d] = oacc[td][r] * (mv/128) / lrun
    const float inv = (mv * 0.0078125f) / lrun;
    float lmax = 0.0f;
    #pragma unroll
    for (int td = 0; td < 4; td++) {
        float4 o;
        o.x = oacc[td][0] * inv;
        o.y = oacc[td][1] * inv;
        o.z = oacc[td][2] * inv;
        o.w = oacc[td][3] * inv;
        lmax = fmaxf(lmax, fmaxf(fmaxf(fabsf(o.x), fabsf(o.y)), fmaxf(fabsf(o.z), fabsf(o.w))));
        *(float4*)&Out[baseQ + (size_t)qg * DMODEL + td * 16 + qd * 4] = o;
    }
    block_max_atomic(lmax, red, moSlot);
}

// ---------- launcher ----------
extern "C" void kernel_launch(void* const* d_in, const int* in_sizes, int n_in,
                              void* d_out, int out_size, void* d_ws, size_t ws_size,
                              hipStream_t stream) {
    const float* x  = (const float*)d_in[0];
    const float* Wq = (const float*)d_in[1];
    const float* bq = (const float*)d_in[2];
    const float* Wk = (const float*)d_in[3];
    const float* bk = (const float*)d_in[4];
    const float* Wv = (const float*)d_in[5];
    const float* bv = (const float*)d_in[6];
    const float* Wo = (const float*)d_in[7];
    const float* bo = (const float*)d_in[8];
    float* out = (float*)d_out;

    const size_t MB = 1024 * 1024;
    unsigned int* slots = (unsigned int*)d_ws;
    char* p = (char*)d_ws + 256;
    unsigned short* WqH = (unsigned short*)(p + 0 * MB);
    unsigned short* WqL = (unsigned short*)(p + 2 * MB);
    unsigned short* WkH = (unsigned short*)(p + 4 * MB);
    unsigned short* WkL = (unsigned short*)(p + 6 * MB);
    unsigned short* WvH = (unsigned short*)(p + 8 * MB);
    unsigned short* WvL = (unsigned short*)(p + 10 * MB);
    unsigned short* WoH = (unsigned short*)(p + 12 * MB);
    unsigned short* WoL = (unsigned short*)(p + 14 * MB);
    unsigned short* Xi  = (unsigned short*)(p + 16 * MB);  // 8 MB, x as int-bf16
    float* RA  = (float*)(p + 24 * MB);                    // 16 MB: Kraw -> Qraw -> Oi
    float* RB  = (float*)(p + 40 * MB);                    // 16 MB: Vraw -> attn-out raw
    unsigned short* Vti = (unsigned short*)(p + 56 * MB);  // 8 MB, V^T int-bf16
    unsigned short* Ki  = (unsigned short*)(p + 4 * MB);   // 8 MB, overlays Wk/Wv splits (dead)
    unsigned short* Oi  = (unsigned short*)RA;             // 8 MB, overlays Qraw (dead)

    hipMemsetAsync(d_ws, 0, 256, stream);  // zero max slots

    wsplit_kernel<<<dim3(1024, 4), 256, 0, stream>>>(Wq, Wk, Wv, Wo,
        WqH, WqL, WkH, WkL, WvH, WvL, WoH, WoL);
    absmax_kernel<<<1024, 256, 0, stream>>>(x, N4, slots + 0);
    quant_int_kernel<<<1024, 256, 0, stream>>>(x, Xi, slots + 0, N4);

    // K and V projections (z=0: K, z=1: V); raw fp32 out + global max
    gemm_mfma<128><<<dim3(8, 32, 2), 256, 0, stream>>>(Xi, slots + 0,
        WkH, WkL, bk, RA, slots + 2,
        WvH, WvL, bv, RB, slots + 3);
    quant_int_kernel<<<1024, 256, 0, stream>>>(RA, Ki, slots + 2, N4);
    vtrans_quant<<<dim3(32, 32), 256, 0, stream>>>(RB, Vti, slots + 3);

    // Q projection (raw into RA, over dead Kraw)
    gemm_mfma<128><<<dim3(8, 32, 1), 256, 0, stream>>>(Xi, slots + 0,
        WqH, WqL, bq, RA, slots + 1,
        WqH, WqL, bq, RA, slots + 1);

    // attention: raw out into RB (over dead Vraw), slot4 = max|attn out|
    attn_mfma<<<dim3(32, 32), 256, 0, stream>>>(RA, Ki, Vti, slots, RB, slots + 4);
    quant_int_kernel<<<1024, 256, 0, stream>>>(RB, Oi, slots + 4, N4);

    // O projection straight into d_out (raw), then final fake-quant in place
    gemm_mfma<128><<<dim3(8, 32, 1), 256, 0, stream>>>(Oi, slots + 4,
        WoH, WoL, bo, out, slots + 5,
        WoH, WoL, bo, out, slots + 5);
    quant_out_kernel<<<1024, 256, 0, stream>>>(out, slots + 5, N4);
}

// Round 6
// 360.253 us; speedup vs baseline: 1.7391x; 1.0632x over previous
//
#include <hip/hip_runtime.h>
#include <math.h>

#define DMODEL 1024
#define SEQ    2048
#define NELEM  4194304   // B*S*d
#define N4     (NELEM / 4)

typedef __attribute__((ext_vector_type(8))) short short8;    // 8 bf16 (4 VGPRs)
typedef __attribute__((ext_vector_type(4))) short short4v;   // 4 bf16 (2 VGPRs)
typedef __attribute__((ext_vector_type(4))) float f32x4;     // C/D frag

#define EXP2(x) exp2f(x)

// async 16B global->LDS (DMA): LDS dest = wave-uniform base + lane*16
__device__ __forceinline__ void gl2lds16(const unsigned short* g, unsigned short* l) {
    __builtin_amdgcn_global_load_lds(
        (const __attribute__((address_space(1))) unsigned int*)g,
        (__attribute__((address_space(3))) unsigned int*)l,
        16, 0, 0);
}

// ---------- numeric helpers (bit-exact vs numpy reference) ----------
__device__ __forceinline__ float fq(float x, float m) {
    float t = x / m * 128.0f;      // correctly-rounded div, exact *128
    float r = rintf(t);            // half-even == np.round
    float q = r * 0.0078125f * m;
    return (m > 0.0f) ? q : x;
}
__device__ __forceinline__ unsigned short f2bf(float f) {   // RNE float->bf16 bits
    unsigned int u = __float_as_uint(f);
    u += 0x7FFFu + ((u >> 16) & 1u);
    return (unsigned short)(u >> 16);
}
__device__ __forceinline__ float bf2f(unsigned short h) {
    return __uint_as_float(((unsigned int)h) << 16);
}
// bf16 bits of rintf(x/m*128): integer in [-128,128] -> exact (truncate works)
__device__ __forceinline__ unsigned short qint(float x, float m) {
    float i = rintf(x / m * 128.0f);
    return (unsigned short)(__float_as_uint(i) >> 16);
}

__device__ __forceinline__ void block_max_atomic(float v, float* red, unsigned int* slot) {
    const int t = threadIdx.x;
    red[t] = v;
    __syncthreads();
    #pragma unroll
    for (int s = 128; s > 0; s >>= 1) {
        if (t < s) red[t] = fmaxf(red[t], red[t + s]);
        __syncthreads();
    }
    if (t == 0) atomicMax(slot, __float_as_uint(red[0]));   // bits monotone for >=0
}

// ---------- elementwise kernels ----------
__global__ __launch_bounds__(256) void absmax_kernel(const float* __restrict__ x, int n4,
                                                     unsigned int* __restrict__ slot) {
    __shared__ float red[256];
    float m = 0.0f;
    const float4* x4 = (const float4*)x;
    for (int i = blockIdx.x * 256 + threadIdx.x; i < n4; i += gridDim.x * 256) {
        float4 v = x4[i];
        m = fmaxf(m, fmaxf(fmaxf(fabsf(v.x), fabsf(v.y)), fmaxf(fabsf(v.z), fabsf(v.w))));
    }
    block_max_atomic(m, red, slot);
}

__global__ __launch_bounds__(256) void quant_int_kernel(const float* __restrict__ src,
                                                        unsigned short* __restrict__ dst,
                                                        const unsigned int* __restrict__ slot,
                                                        int n4) {
    const float m = __uint_as_float(*slot);
    const float4* s4 = (const float4*)src;
    for (int i = blockIdx.x * 256 + threadIdx.x; i < n4; i += gridDim.x * 256) {
        float4 v = s4[i];
        ushort4 o;
        o.x = qint(v.x, m); o.y = qint(v.y, m); o.z = qint(v.z, m); o.w = qint(v.w, m);
        ((ushort4*)dst)[i] = o;
    }
}

__global__ __launch_bounds__(256) void quant_out_kernel(float* __restrict__ Y,
                                                        const unsigned int* __restrict__ slot,
                                                        int n4) {
    const float m = __uint_as_float(*slot);
    float4* y4 = (float4*)Y;
    for (int i = blockIdx.x * 256 + threadIdx.x; i < n4; i += gridDim.x * 256) {
        float4 v = y4[i];
        v.x = fq(v.x, m); v.y = fq(v.y, m); v.z = fq(v.z, m); v.w = fq(v.w, m);
        y4[i] = v;
    }
}

// Split 4 weight matrices into bf16 hi+lo (W ~= hi+lo, residual ~2^-18 rel)
__global__ __launch_bounds__(256) void wsplit_kernel(
    const float* __restrict__ W0, const float* __restrict__ W1,
    const float* __restrict__ W2, const float* __restrict__ W3,
    unsigned short* __restrict__ H0, unsigned short* __restrict__ L0,
    unsigned short* __restrict__ H1, unsigned short* __restrict__ L1,
    unsigned short* __restrict__ H2, unsigned short* __restrict__ L2,
    unsigned short* __restrict__ H3, unsigned short* __restrict__ L3) {
    const int z = blockIdx.y;
    const float* W = (z == 0) ? W0 : (z == 1) ? W1 : (z == 2) ? W2 : W3;
    unsigned short* H = (z == 0) ? H0 : (z == 1) ? H1 : (z == 2) ? H2 : H3;
    unsigned short* L = (z == 0) ? L0 : (z == 1) ? L1 : (z == 2) ? L2 : L3;
    const int i = blockIdx.x * 256 + threadIdx.x;   // grid.x*256 == 1024*1024/4
    float4 w = ((const float4*)W)[i];
    ushort4 h, l;
    h.x = f2bf(w.x); l.x = f2bf(w.x - bf2f(h.x));
    h.y = f2bf(w.y); l.y = f2bf(w.y - bf2f(h.y));
    h.z = f2bf(w.z); l.z = f2bf(w.z - bf2f(h.z));
    h.w = f2bf(w.w); l.w = f2bf(w.w - bf2f(h.w));
    ((ushort4*)H)[i] = h;
    ((ushort4*)L)[i] = l;
}

// V: [b][s][1024] fp32 raw -> Vti [bh][64 d][2048 s] bf16-int (transposed for PV A-frags)
__global__ __launch_bounds__(256) void vtrans_quant(const float* __restrict__ Vraw,
                                                    unsigned short* __restrict__ Vti,
                                                    const unsigned int* __restrict__ slot) {
    __shared__ float tile[64][65];
    const float mv = __uint_as_float(*slot);
    const int t = threadIdx.x;
    const int s0 = blockIdx.x << 6;
    const int bh = blockIdx.y;
    const int b = bh >> 4, h = bh & 15;
    const int rr = t >> 4;            // 0..15
    const int cc = (t & 15) << 2;     // 0..60
    #pragma unroll
    for (int rep = 0; rep < 4; rep++) {
        int srow = rep * 16 + rr;
        float4 v = *(const float4*)&Vraw[(size_t)b * SEQ * DMODEL + (size_t)(s0 + srow) * DMODEL + h * 64 + cc];
        tile[srow][cc + 0] = v.x; tile[srow][cc + 1] = v.y;
        tile[srow][cc + 2] = v.z; tile[srow][cc + 3] = v.w;
    }
    __syncthreads();
    #pragma unroll
    for (int rep = 0; rep < 4; rep++) {
        int drow = rep * 16 + rr;
        ushort4 o;
        o.x = qint(tile[cc + 0][drow], mv);
        o.y = qint(tile[cc + 1][drow], mv);
        o.z = qint(tile[cc + 2][drow], mv);
        o.w = qint(tile[cc + 3][drow], mv);
        *(ushort4*)&Vti[(size_t)bh * 64 * SEQ + (size_t)drow * SEQ + s0 + cc] = o;
    }
}

// ---------- MFMA GEMM: y = (mA/128) * (iA @ (Whi+Wlo)^T) + b ----------
// BM=128, BN=128, BK=32. 4 waves as 2x2. m97 recipe: global_load_lds width=16
// into UNPADDED 128x32-ushort LDS arrays (wave-uniform dst base + lane*16B),
// ds_read_b128 fragment reads at 64B row stride.
__global__ __launch_bounds__(256) void gemm_mfma(
    const unsigned short* __restrict__ Ai, const unsigned int* __restrict__ mSlot,
    const unsigned short* __restrict__ Wh0, const unsigned short* __restrict__ Wl0,
    const float* __restrict__ b0, float* __restrict__ O0, unsigned int* __restrict__ s0,
    const unsigned short* __restrict__ Wh1, const unsigned short* __restrict__ Wl1,
    const float* __restrict__ b1, float* __restrict__ O1, unsigned int* __restrict__ s1) {
    __shared__ __align__(16) unsigned short As[128 * 32];
    __shared__ __align__(16) unsigned short Bh[128 * 32];
    __shared__ __align__(16) unsigned short Bl[128 * 32];
    __shared__ float red[256];

    const int z = blockIdx.z;
    const unsigned short* Wh = z ? Wh1 : Wh0;
    const unsigned short* Wl = z ? Wl1 : Wl0;
    const float* bias = z ? b1 : b0;
    float* O = z ? O1 : O0;
    unsigned int* slotOut = z ? s1 : s0;

    const float mA = __uint_as_float(*mSlot);
    const int t = threadIdx.x;
    const int lane = t & 63, w = t >> 6;
    const int ml = lane & 15, qd = lane >> 4;
    const int wm = w & 1, wn = w >> 1;
    const int m0 = blockIdx.y << 7;
    const int n0 = blockIdx.x << 7;

    // staging: wave w owns rows [w*32, w*32+32) of each array, 2 instrs of 16 rows.
    // lane i supplies row w*32 + j*16 + (i>>2), 16B chunk (i&3) -> LDS base + i*16B.
    const int lr = lane >> 2;           // 0..15
    const int lc = (lane & 3) << 3;     // ushort col 0,8,16,24
    const unsigned short* Asrc = Ai + (size_t)(m0 + w * 32 + lr) * DMODEL + lc;
    const unsigned short* Hsrc = Wh + (size_t)(n0 + w * 32 + lr) * DMODEL + lc;
    const unsigned short* Lsrc = Wl + (size_t)(n0 + w * 32 + lr) * DMODEL + lc;
    unsigned short* Adst = &As[(w * 32) * 32];
    unsigned short* Hdst = &Bh[(w * 32) * 32];
    unsigned short* Ldst = &Bl[(w * 32) * 32];

    f32x4 acc[4][4];
    #pragma unroll
    for (int mi = 0; mi < 4; mi++)
        #pragma unroll
        for (int ni = 0; ni < 4; ni++) acc[mi][ni] = (f32x4){0.f, 0.f, 0.f, 0.f};

    for (int k0 = 0; k0 < DMODEL; k0 += 32) {
        __syncthreads();                 // previous iter's LDS reads done
        gl2lds16(Asrc + k0,               Adst);
        gl2lds16(Asrc + k0 + 16 * DMODEL, Adst + 16 * 32);
        gl2lds16(Hsrc + k0,               Hdst);
        gl2lds16(Hsrc + k0 + 16 * DMODEL, Hdst + 16 * 32);
        gl2lds16(Lsrc + k0,               Ldst);
        gl2lds16(Lsrc + k0 + 16 * DMODEL, Ldst + 16 * 32);
        __syncthreads();                 // barrier drains vmcnt -> LDS visible

        short8 af[4];
        #pragma unroll
        for (int mi = 0; mi < 4; mi++)
            af[mi] = *(const short8*)&As[(wm * 64 + mi * 16 + ml) * 32 + qd * 8];
        #pragma unroll
        for (int ni = 0; ni < 4; ni++) {
            short8 bh = *(const short8*)&Bh[(wn * 64 + ni * 16 + ml) * 32 + qd * 8];
            short8 bl = *(const short8*)&Bl[(wn * 64 + ni * 16 + ml) * 32 + qd * 8];
            #pragma unroll
            for (int mi = 0; mi < 4; mi++) {
                acc[mi][ni] = __builtin_amdgcn_mfma_f32_16x16x32_bf16(af[mi], bh, acc[mi][ni], 0, 0, 0);
                acc[mi][ni] = __builtin_amdgcn_mfma_f32_16x16x32_bf16(af[mi], bl, acc[mi][ni], 0, 0, 0);
            }
        }
    }

    const float s = mA * 0.0078125f;
    float lmax = 0.0f;
    #pragma unroll
    for (int ni = 0; ni < 4; ni++) {
        const int col = n0 + wn * 64 + ni * 16 + ml;
        const float bc = bias[col];
        #pragma unroll
        for (int mi = 0; mi < 4; mi++) {
            #pragma unroll
            for (int r = 0; r < 4; r++) {
                int row = m0 + wm * 64 + mi * 16 + qd * 4 + r;
                float v = acc[mi][ni][r] * s + bc;
                lmax = fmaxf(lmax, fabsf(v));
                O[row * DMODEL + col] = v;
            }
        }
    }
    block_max_atomic(lmax, red, slotOut);
}

// ---------- MFMA flash attention: transposed S^T = K Q^T + LDS-staged K/V ----------
// WG = 4 waves; wave w owns q-cols [q0+w*16, q0+w*16+16). K/V tiles staged
// cooperatively (coalesced) into LDS each k-iter; A-frags via ds_read.
// S^T C-layout puts all 16 scores of one q-col in-lane -> in-lane softmax;
// P^T is ALREADY the K=16 MFMA B-operand layout -> PV needs no cross-lane ops.
__global__ __launch_bounds__(256) void attn_mfma(
    const float* __restrict__ Qraw, const unsigned short* __restrict__ Ki,
    const unsigned short* __restrict__ Vti, const unsigned int* __restrict__ slots,
    float* __restrict__ Out, unsigned int* __restrict__ moSlot) {
    __shared__ __align__(16) unsigned short Ks[64 * 72];   // [k][d], 9 KB
    __shared__ __align__(16) unsigned short Vt[64 * 72];   // [d][k], 9 KB
    __shared__ float red[256];
    union U8 { short8 v; unsigned short u[8]; };
    union U4 { short4v v; unsigned short u[4]; };

    const int t = threadIdx.x;
    const int lane = t & 63, w = t >> 6;
    const int ml = lane & 15, qd = lane >> 4;
    const int q0 = blockIdx.x << 6;
    const int bh = blockIdx.y;
    const int b = bh >> 4, h = bh & 15;
    const float mq = __uint_as_float(slots[1]);
    const float mk = __uint_as_float(slots[2]);
    const float mv = __uint_as_float(slots[3]);
    // score scale folded with log2(e): p = exp2((s_acc - m_acc)*c2)
    const float c2 = (mq * 0.0078125f) * (mk * 0.0078125f) * 0.125f * 1.4426950408889634f;
    const int baseQ = b * SEQ * DMODEL + h * 64;
    const int qg = q0 + w * 16 + ml;

    // Q B-frags (quantize once from raw): bq[c] holds Q[qg][c*32 + qd*8 + j]
    short8 bq[2];
    {
        const float* src = Qraw + baseQ + qg * DMODEL + qd * 8;
        #pragma unroll
        for (int c = 0; c < 2; c++) {
            float4 v0 = *(const float4*)(src + c * 32);
            float4 v1 = *(const float4*)(src + c * 32 + 4);
            U8 tmp;
            tmp.u[0] = qint(v0.x, mq); tmp.u[1] = qint(v0.y, mq);
            tmp.u[2] = qint(v0.z, mq); tmp.u[3] = qint(v0.w, mq);
            tmp.u[4] = qint(v1.x, mq); tmp.u[5] = qint(v1.y, mq);
            tmp.u[6] = qint(v1.z, mq); tmp.u[7] = qint(v1.w, mq);
            bq[c] = tmp.v;
        }
    }

    f32x4 oacc[4];
    #pragma unroll
    for (int i = 0; i < 4; i++) oacc[i] = (f32x4){0.f, 0.f, 0.f, 0.f};
    float mrun = -INFINITY, lrun = 0.0f;

    // cooperative staging indices: thread t loads row r = t>>2, 32B segment (t&3)
    const int sr = t >> 2;
    const int sc = (t & 3) << 4;            // ushort offset 0,16,32,48
    const unsigned short* kstage = Ki + baseQ + (size_t)sr * DMODEL + sc;
    const unsigned short* vstage = Vti + (size_t)bh * 64 * SEQ + (size_t)sr * SEQ + sc;

    for (int k0 = 0; k0 < SEQ; k0 += 64) {
        __syncthreads();   // protect LDS reuse from previous iteration
        *(short8*)&Ks[sr * 72 + sc]     = *(const short8*)(kstage + (size_t)k0 * DMODEL);
        *(short8*)&Ks[sr * 72 + sc + 8] = *(const short8*)(kstage + (size_t)k0 * DMODEL + 8);
        *(short8*)&Vt[sr * 72 + sc]     = *(const short8*)(vstage + k0);
        *(short8*)&Vt[sr * 72 + sc + 8] = *(const short8*)(vstage + k0 + 8);
        __syncthreads();

        // ---- S^T tile: A=K rows (kk), B=Q. sacc[tau][r] = S^T[k0+tau*16+qd*4+r][qg]
        f32x4 sacc[4];
        #pragma unroll
        for (int tau = 0; tau < 4; tau++) {
            short8 a0 = *(const short8*)&Ks[(tau * 16 + ml) * 72 + qd * 8];
            short8 a1 = *(const short8*)&Ks[(tau * 16 + ml) * 72 + 32 + qd * 8];
            f32x4 z4 = (f32x4){0.f, 0.f, 0.f, 0.f};
            z4 = __builtin_amdgcn_mfma_f32_16x16x32_bf16(a0, bq[0], z4, 0, 0, 0);
            sacc[tau] = __builtin_amdgcn_mfma_f32_16x16x32_bf16(a1, bq[1], z4, 0, 0, 0);
        }

        // ---- online softmax: all 16 scores of q-col qg live in this lane
        float tmax = fmaxf(fmaxf(fmaxf(sacc[0][0], sacc[0][1]), fmaxf(sacc[0][2], sacc[0][3])),
                           fmaxf(fmaxf(sacc[1][0], sacc[1][1]), fmaxf(sacc[1][2], sacc[1][3])));
        tmax = fmaxf(tmax, fmaxf(fmaxf(fmaxf(sacc[2][0], sacc[2][1]), fmaxf(sacc[2][2], sacc[2][3])),
                                 fmaxf(fmaxf(sacc[3][0], sacc[3][1]), fmaxf(sacc[3][2], sacc[3][3]))));
        tmax = fmaxf(tmax, __shfl_xor(tmax, 16));
        tmax = fmaxf(tmax, __shfl_xor(tmax, 32));
        const float mnew = fmaxf(mrun, tmax);
        const float alpha = EXP2((mrun - mnew) * c2);
        const float mc = mnew * c2;
        float p[4][4];
        float ls = 0.0f;
        #pragma unroll
        for (int tau = 0; tau < 4; tau++)
            #pragma unroll
            for (int r = 0; r < 4; r++) {
                float pv = EXP2(sacc[tau][r] * c2 - mc);
                p[tau][r] = pv;
                ls += pv;
            }
        ls += __shfl_xor(ls, 16);
        ls += __shfl_xor(ls, 32);
        lrun = lrun * alpha + ls;
        mrun = mnew;

        // ---- split P into bf16 hi/lo: p[tau][0..3] is ALREADY the K=16 B-frag
        short4v phi[4], plo[4];
        #pragma unroll
        for (int tau = 0; tau < 4; tau++) {
            U4 hh, ll;
            #pragma unroll
            for (int r = 0; r < 4; r++) {
                unsigned int u = __float_as_uint(p[tau][r]);
                unsigned int uh = (u + 0x8000u) & 0xFFFF0000u;   // round-to-nearest hi
                hh.u[r] = (unsigned short)(uh >> 16);
                float lf = p[tau][r] - __uint_as_float(uh);      // exact residual
                ll.u[r] = (unsigned short)(__float_as_uint(lf) >> 16);  // trunc lo
            }
            phi[tau] = hh.v;
            plo[tau] = ll.v;
        }

        // ---- rescale O
        #pragma unroll
        for (int i = 0; i < 4; i++) {
            oacc[i][0] *= alpha; oacc[i][1] *= alpha;
            oacc[i][2] *= alpha; oacc[i][3] *= alpha;
        }

        // ---- O^T += V^T P^T via K=16 MFMA (A = V^T 8B frags from LDS)
        #pragma unroll
        for (int td = 0; td < 4; td++) {
            #pragma unroll
            for (int tau = 0; tau < 4; tau++) {
                short4v av = *(const short4v*)&Vt[(td * 16 + ml) * 72 + tau * 16 + qd * 4];
                oacc[td] = __builtin_amdgcn_mfma_f32_16x16x16bf16_1k(av, phi[tau], oacc[td], 0, 0, 0);
                oacc[td] = __builtin_amdgcn_mfma_f32_16x16x16bf16_1k(av, plo[tau], oacc[td], 0, 0, 0);
            }
        }
    }

    // ---- epilogue: O[qg][d] = oacc[td][r] * (mv/128) / lrun
    const float inv = (mv * 0.0078125f) / lrun;
    float lmax = 0.0f;
    #pragma unroll
    for (int td = 0; td < 4; td++) {
        float4 o;
        o.x = oacc[td][0] * inv;
        o.y = oacc[td][1] * inv;
        o.z = oacc[td][2] * inv;
        o.w = oacc[td][3] * inv;
        lmax = fmaxf(lmax, fmaxf(fmaxf(fabsf(o.x), fabsf(o.y)), fmaxf(fabsf(o.z), fabsf(o.w))));
        *(float4*)&Out[baseQ + (size_t)qg * DMODEL + td * 16 + qd * 4] = o;
    }
    block_max_atomic(lmax, red, moSlot);
}

// ---------- launcher ----------
extern "C" void kernel_launch(void* const* d_in, const int* in_sizes, int n_in,
                              void* d_out, int out_size, void* d_ws, size_t ws_size,
                              hipStream_t stream) {
    const float* x  = (const float*)d_in[0];
    const float* Wq = (const float*)d_in[1];
    const float* bq = (const float*)d_in[2];
    const float* Wk = (const float*)d_in[3];
    const float* bk = (const float*)d_in[4];
    const float* Wv = (const float*)d_in[5];
    const float* bv = (const float*)d_in[6];
    const float* Wo = (const float*)d_in[7];
    const float* bo = (const float*)d_in[8];
    float* out = (float*)d_out;

    const size_t MB = 1024 * 1024;
    unsigned int* slots = (unsigned int*)d_ws;
    char* p = (char*)d_ws + 256;
    unsigned short* WqH = (unsigned short*)(p + 0 * MB);
    unsigned short* WqL = (unsigned short*)(p + 2 * MB);
    unsigned short* WkH = (unsigned short*)(p + 4 * MB);
    unsigned short* WkL = (unsigned short*)(p + 6 * MB);
    unsigned short* WvH = (unsigned short*)(p + 8 * MB);
    unsigned short* WvL = (unsigned short*)(p + 10 * MB);
    unsigned short* WoH = (unsigned short*)(p + 12 * MB);
    unsigned short* WoL = (unsigned short*)(p + 14 * MB);
    unsigned short* Xi  = (unsigned short*)(p + 16 * MB);  // 8 MB, x as int-bf16
    float* RA  = (float*)(p + 24 * MB);                    // 16 MB: Kraw -> Qraw -> Oi
    float* RB  = (float*)(p + 40 * MB);                    // 16 MB: Vraw -> attn-out raw
    unsigned short* Vti = (unsigned short*)(p + 56 * MB);  // 8 MB, V^T int-bf16
    unsigned short* Ki  = (unsigned short*)(p + 4 * MB);   // 8 MB, overlays Wk/Wv splits (dead)
    unsigned short* Oi  = (unsigned short*)RA;             // 8 MB, overlays Qraw (dead)

    hipMemsetAsync(d_ws, 0, 256, stream);  // zero max slots

    wsplit_kernel<<<dim3(1024, 4), 256, 0, stream>>>(Wq, Wk, Wv, Wo,
        WqH, WqL, WkH, WkL, WvH, WvL, WoH, WoL);
    absmax_kernel<<<1024, 256, 0, stream>>>(x, N4, slots + 0);
    quant_int_kernel<<<1024, 256, 0, stream>>>(x, Xi, slots + 0, N4);

    // K and V projections (z=0: K, z=1: V); raw fp32 out + global max
    gemm_mfma<<<dim3(8, 32, 2), 256, 0, stream>>>(Xi, slots + 0,
        WkH, WkL, bk, RA, slots + 2,
        WvH, WvL, bv, RB, slots + 3);
    quant_int_kernel<<<1024, 256, 0, stream>>>(RA, Ki, slots + 2, N4);
    vtrans_quant<<<dim3(32, 32), 256, 0, stream>>>(RB, Vti, slots + 3);

    // Q projection (raw into RA, over dead Kraw)
    gemm_mfma<<<dim3(8, 32, 1), 256, 0, stream>>>(Xi, slots + 0,
        WqH, WqL, bq, RA, slots + 1,
        WqH, WqL, bq, RA, slots + 1);

    // attention: raw out into RB (over dead Vraw), slot4 = max|attn out|
    attn_mfma<<<dim3(32, 32), 256, 0, stream>>>(RA, Ki, Vti, slots, RB, slots + 4);
    quant_int_kernel<<<1024, 256, 0, stream>>>(RB, Oi, slots + 4, N4);

    // O projection straight into d_out (raw), then final fake-quant in place
    gemm_mfma<<<dim3(8, 32, 1), 256, 0, stream>>>(Oi, slots + 4,
        WoH, WoL, bo, out, slots + 5,
        WoH, WoL, bo, out, slots + 5);
    quant_out_kernel<<<1024, 256, 0, stream>>>(out, slots + 5, N4);
}

// Round 7
// 341.114 us; speedup vs baseline: 1.8367x; 1.0561x over previous
//
#include <hip/hip_runtime.h>
#include <math.h>

#define DMODEL 1024
#define SEQ    2048
#define NELEM  4194304   // B*S*d
#define N4     (NELEM / 4)

typedef __attribute__((ext_vector_type(8))) short short8;    // 8 bf16 (4 VGPRs)
typedef __attribute__((ext_vector_type(4))) short short4v;   // 4 bf16 (2 VGPRs)
typedef __attribute__((ext_vector_type(4))) float f32x4;     // C/D frag

#if __has_builtin(__builtin_amdgcn_exp2f)
#define EXP2(x) __builtin_amdgcn_exp2f(x)   // raw v_exp_f32, <=2 ulp
#else
#define EXP2(x) exp2f(x)
#endif

// async 16B global->LDS (DMA): LDS dest = wave-uniform base + lane*16
__device__ __forceinline__ void gl2lds16(const unsigned short* g, unsigned short* l) {
    __builtin_amdgcn_global_load_lds(
        (const __attribute__((address_space(1))) unsigned int*)g,
        (__attribute__((address_space(3))) unsigned int*)l,
        16, 0, 0);
}

// ---------- numeric helpers (bit-exact vs numpy reference) ----------
__device__ __forceinline__ float fq(float x, float m) {
    float t = x / m * 128.0f;      // correctly-rounded div, exact *128
    float r = rintf(t);            // half-even == np.round
    float q = r * 0.0078125f * m;
    return (m > 0.0f) ? q : x;
}
__device__ __forceinline__ unsigned short f2bf(float f) {   // RNE float->bf16 bits
    unsigned int u = __float_as_uint(f);
    u += 0x7FFFu + ((u >> 16) & 1u);
    return (unsigned short)(u >> 16);
}
__device__ __forceinline__ float bf2f(unsigned short h) {
    return __uint_as_float(((unsigned int)h) << 16);
}
// bf16 bits of rintf(x/m*128): integer in [-128,128] -> exact (truncate works)
__device__ __forceinline__ unsigned short qint(float x, float m) {
    float i = rintf(x / m * 128.0f);
    return (unsigned short)(__float_as_uint(i) >> 16);
}

__device__ __forceinline__ void block_max_atomic(float v, float* red, unsigned int* slot) {
    const int t = threadIdx.x;
    red[t] = v;
    __syncthreads();
    #pragma unroll
    for (int s = 128; s > 0; s >>= 1) {
        if (t < s) red[t] = fmaxf(red[t], red[t + s]);
        __syncthreads();
    }
    if (t == 0) atomicMax(slot, __float_as_uint(red[0]));   // bits monotone for >=0
}

// ---------- elementwise kernels ----------
__global__ __launch_bounds__(256) void absmax_kernel(const float* __restrict__ x, int n4,
                                                     unsigned int* __restrict__ slot) {
    __shared__ float red[256];
    float m = 0.0f;
    const float4* x4 = (const float4*)x;
    for (int i = blockIdx.x * 256 + threadIdx.x; i < n4; i += gridDim.x * 256) {
        float4 v = x4[i];
        m = fmaxf(m, fmaxf(fmaxf(fabsf(v.x), fabsf(v.y)), fmaxf(fabsf(v.z), fabsf(v.w))));
    }
    block_max_atomic(m, red, slot);
}

__global__ __launch_bounds__(256) void quant_int_kernel(const float* __restrict__ src,
                                                        unsigned short* __restrict__ dst,
                                                        const unsigned int* __restrict__ slot,
                                                        int n4) {
    const float m = __uint_as_float(*slot);
    const float4* s4 = (const float4*)src;
    for (int i = blockIdx.x * 256 + threadIdx.x; i < n4; i += gridDim.x * 256) {
        float4 v = s4[i];
        ushort4 o;
        o.x = qint(v.x, m); o.y = qint(v.y, m); o.z = qint(v.z, m); o.w = qint(v.w, m);
        ((ushort4*)dst)[i] = o;
    }
}

__global__ __launch_bounds__(256) void quant_out_kernel(float* __restrict__ Y,
                                                        const unsigned int* __restrict__ slot,
                                                        int n4) {
    const float m = __uint_as_float(*slot);
    float4* y4 = (float4*)Y;
    for (int i = blockIdx.x * 256 + threadIdx.x; i < n4; i += gridDim.x * 256) {
        float4 v = y4[i];
        v.x = fq(v.x, m); v.y = fq(v.y, m); v.z = fq(v.z, m); v.w = fq(v.w, m);
        y4[i] = v;
    }
}

// Split 4 weight matrices into bf16 hi+lo (W ~= hi+lo, residual ~2^-18 rel)
__global__ __launch_bounds__(256) void wsplit_kernel(
    const float* __restrict__ W0, const float* __restrict__ W1,
    const float* __restrict__ W2, const float* __restrict__ W3,
    unsigned short* __restrict__ H0, unsigned short* __restrict__ L0,
    unsigned short* __restrict__ H1, unsigned short* __restrict__ L1,
    unsigned short* __restrict__ H2, unsigned short* __restrict__ L2,
    unsigned short* __restrict__ H3, unsigned short* __restrict__ L3) {
    const int z = blockIdx.y;
    const float* W = (z == 0) ? W0 : (z == 1) ? W1 : (z == 2) ? W2 : W3;
    unsigned short* H = (z == 0) ? H0 : (z == 1) ? H1 : (z == 2) ? H2 : H3;
    unsigned short* L = (z == 0) ? L0 : (z == 1) ? L1 : (z == 2) ? L2 : L3;
    const int i = blockIdx.x * 256 + threadIdx.x;   // grid.x*256 == 1024*1024/4
    float4 w = ((const float4*)W)[i];
    ushort4 h, l;
    h.x = f2bf(w.x); l.x = f2bf(w.x - bf2f(h.x));
    h.y = f2bf(w.y); l.y = f2bf(w.y - bf2f(h.y));
    h.z = f2bf(w.z); l.z = f2bf(w.z - bf2f(h.z));
    h.w = f2bf(w.w); l.w = f2bf(w.w - bf2f(h.w));
    ((ushort4*)H)[i] = h;
    ((ushort4*)L)[i] = l;
}

// V: [b][s][1024] fp32 raw -> Vti [bh][64 d][2048 s] bf16-int (transposed for PV A-frags)
__global__ __launch_bounds__(256) void vtrans_quant(const float* __restrict__ Vraw,
                                                    unsigned short* __restrict__ Vti,
                                                    const unsigned int* __restrict__ slot) {
    __shared__ float tile[64][65];
    const float mv = __uint_as_float(*slot);
    const int t = threadIdx.x;
    const int s0 = blockIdx.x << 6;
    const int bh = blockIdx.y;
    const int b = bh >> 4, h = bh & 15;
    const int rr = t >> 4;            // 0..15
    const int cc = (t & 15) << 2;     // 0..60
    #pragma unroll
    for (int rep = 0; rep < 4; rep++) {
        int srow = rep * 16 + rr;
        float4 v = *(const float4*)&Vraw[(size_t)b * SEQ * DMODEL + (size_t)(s0 + srow) * DMODEL + h * 64 + cc];
        tile[srow][cc + 0] = v.x; tile[srow][cc + 1] = v.y;
        tile[srow][cc + 2] = v.z; tile[srow][cc + 3] = v.w;
    }
    __syncthreads();
    #pragma unroll
    for (int rep = 0; rep < 4; rep++) {
        int drow = rep * 16 + rr;
        ushort4 o;
        o.x = qint(tile[cc + 0][drow], mv);
        o.y = qint(tile[cc + 1][drow], mv);
        o.z = qint(tile[cc + 2][drow], mv);
        o.w = qint(tile[cc + 3][drow], mv);
        *(ushort4*)&Vti[(size_t)bh * 64 * SEQ + (size_t)drow * SEQ + s0 + cc] = o;
    }
}

// ---------- MFMA GEMM: y = (mA/128) * (iA @ (Whi+Wlo)^T) + b ----------
// BM=128, BN in {64,128}, BK=32. 4 waves as 2x2. m97 recipe: global_load_lds
// width=16 into UNPADDED row-major LDS (wave-uniform dst base + lane*16B),
// ds_read_b128 fragment reads at 64B row stride. BN=64 doubles the grid for
// N=1024 problems (2 WG/CU instead of 1 -> cross-block barrier overlap).
template<int BN>
__global__ __launch_bounds__(256) void gemm_mfma(
    const unsigned short* __restrict__ Ai, const unsigned int* __restrict__ mSlot,
    const unsigned short* __restrict__ Wh0, const unsigned short* __restrict__ Wl0,
    const float* __restrict__ b0, float* __restrict__ O0, unsigned int* __restrict__ s0,
    const unsigned short* __restrict__ Wh1, const unsigned short* __restrict__ Wl1,
    const float* __restrict__ b1, float* __restrict__ O1, unsigned int* __restrict__ s1) {
    constexpr int NI = BN / 32;
    __shared__ __align__(16) unsigned short As[128 * 32];
    __shared__ __align__(16) unsigned short Bh[BN * 32];
    __shared__ __align__(16) unsigned short Bl[BN * 32];
    __shared__ float red[256];

    const int z = blockIdx.z;
    const unsigned short* Wh = z ? Wh1 : Wh0;
    const unsigned short* Wl = z ? Wl1 : Wl0;
    const float* bias = z ? b1 : b0;
    float* O = z ? O1 : O0;
    unsigned int* slotOut = z ? s1 : s0;

    const float mA = __uint_as_float(*mSlot);
    const int t = threadIdx.x;
    const int lane = t & 63, w = t >> 6;
    const int ml = lane & 15, qd = lane >> 4;
    const int wm = w & 1, wn = w >> 1;
    const int m0 = blockIdx.y << 7;
    const int n0 = blockIdx.x * BN;

    // staging: A: wave w owns rows [w*32, w*32+32) (2 instrs of 16 rows).
    // B: wave w owns rows [w*(BN/4), w*(BN/4)+BN/4) (BN/64 instrs per array).
    // lane i supplies row base + j*16 + (i>>2), 16B chunk (i&3) -> LDS base+i*16B.
    const int lr = lane >> 2;           // 0..15
    const int lc = (lane & 3) << 3;     // ushort col 0,8,16,24
    const unsigned short* Asrc = Ai + (size_t)(m0 + w * 32 + lr) * DMODEL + lc;
    const unsigned short* Hsrc = Wh + (size_t)(n0 + w * (BN / 4) + lr) * DMODEL + lc;
    const unsigned short* Lsrc = Wl + (size_t)(n0 + w * (BN / 4) + lr) * DMODEL + lc;
    unsigned short* Adst = &As[(w * 32) * 32];
    unsigned short* Hdst = &Bh[(w * (BN / 4)) * 32];
    unsigned short* Ldst = &Bl[(w * (BN / 4)) * 32];

    f32x4 acc[4][NI];
    #pragma unroll
    for (int mi = 0; mi < 4; mi++)
        #pragma unroll
        for (int ni = 0; ni < NI; ni++) acc[mi][ni] = (f32x4){0.f, 0.f, 0.f, 0.f};

    for (int k0 = 0; k0 < DMODEL; k0 += 32) {
        __syncthreads();                 // previous iter's LDS reads done
        gl2lds16(Asrc + k0,               Adst);
        gl2lds16(Asrc + k0 + 16 * DMODEL, Adst + 16 * 32);
        if constexpr (BN == 128) {
            gl2lds16(Hsrc + k0,               Hdst);
            gl2lds16(Hsrc + k0 + 16 * DMODEL, Hdst + 16 * 32);
            gl2lds16(Lsrc + k0,               Ldst);
            gl2lds16(Lsrc + k0 + 16 * DMODEL, Ldst + 16 * 32);
        } else {
            gl2lds16(Hsrc + k0, Hdst);
            gl2lds16(Lsrc + k0, Ldst);
        }
        __syncthreads();                 // barrier drains vmcnt -> LDS visible

        short8 af[4];
        #pragma unroll
        for (int mi = 0; mi < 4; mi++)
            af[mi] = *(const short8*)&As[(wm * 64 + mi * 16 + ml) * 32 + qd * 8];
        #pragma unroll
        for (int ni = 0; ni < NI; ni++) {
            short8 bh = *(const short8*)&Bh[(wn * (BN / 2) + ni * 16 + ml) * 32 + qd * 8];
            short8 bl = *(const short8*)&Bl[(wn * (BN / 2) + ni * 16 + ml) * 32 + qd * 8];
            #pragma unroll
            for (int mi = 0; mi < 4; mi++) {
                acc[mi][ni] = __builtin_amdgcn_mfma_f32_16x16x32_bf16(af[mi], bh, acc[mi][ni], 0, 0, 0);
                acc[mi][ni] = __builtin_amdgcn_mfma_f32_16x16x32_bf16(af[mi], bl, acc[mi][ni], 0, 0, 0);
            }
        }
    }

    const float s = mA * 0.0078125f;
    float lmax = 0.0f;
    #pragma unroll
    for (int ni = 0; ni < NI; ni++) {
        const int col = n0 + wn * (BN / 2) + ni * 16 + ml;
        const float bc = bias[col];
        #pragma unroll
        for (int mi = 0; mi < 4; mi++) {
            #pragma unroll
            for (int r = 0; r < 4; r++) {
                int row = m0 + wm * 64 + mi * 16 + qd * 4 + r;
                float v = acc[mi][ni][r] * s + bc;
                lmax = fmaxf(lmax, fabsf(v));
                O[row * DMODEL + col] = v;
            }
        }
    }
    block_max_atomic(lmax, red, slotOut);
}

// ---------- MFMA flash attention: transposed S^T = K Q^T + LDS-staged K/V ----------
// WG = 4 waves; wave w owns q-cols [q0+w*16, q0+w*16+16). K/V tiles staged
// cooperatively (coalesced) into LDS each k-iter; A-frags via ds_read.
// S^T C-layout puts all 16 scores of one q-col in-lane -> in-lane softmax;
// P^T is ALREADY the K=16 MFMA B-operand layout -> PV needs no cross-lane ops.
__global__ __launch_bounds__(256) void attn_mfma(
    const float* __restrict__ Qraw, const unsigned short* __restrict__ Ki,
    const unsigned short* __restrict__ Vti, const unsigned int* __restrict__ slots,
    float* __restrict__ Out, unsigned int* __restrict__ moSlot) {
    __shared__ __align__(16) unsigned short Ks[64 * 72];   // [k][d], 9 KB
    __shared__ __align__(16) unsigned short Vt[64 * 72];   // [d][k], 9 KB
    __shared__ float red[256];
    union U8 { short8 v; unsigned short u[8]; };
    union U4 { short4v v; unsigned short u[4]; };

    const int t = threadIdx.x;
    const int lane = t & 63, w = t >> 6;
    const int ml = lane & 15, qd = lane >> 4;
    const int q0 = blockIdx.x << 6;
    const int bh = blockIdx.y;
    const int b = bh >> 4, h = bh & 15;
    const float mq = __uint_as_float(slots[1]);
    const float mk = __uint_as_float(slots[2]);
    const float mv = __uint_as_float(slots[3]);
    // score scale folded with log2(e): p = exp2((s_acc - m_acc)*c2)
    const float c2 = (mq * 0.0078125f) * (mk * 0.0078125f) * 0.125f * 1.4426950408889634f;
    const int baseQ = b * SEQ * DMODEL + h * 64;
    const int qg = q0 + w * 16 + ml;

    // Q B-frags (quantize once from raw): bq[c] holds Q[qg][c*32 + qd*8 + j]
    short8 bq[2];
    {
        const float* src = Qraw + baseQ + qg * DMODEL + qd * 8;
        #pragma unroll
        for (int c = 0; c < 2; c++) {
            float4 v0 = *(const float4*)(src + c * 32);
            float4 v1 = *(const float4*)(src + c * 32 + 4);
            U8 tmp;
            tmp.u[0] = qint(v0.x, mq); tmp.u[1] = qint(v0.y, mq);
            tmp.u[2] = qint(v0.z, mq); tmp.u[3] = qint(v0.w, mq);
            tmp.u[4] = qint(v1.x, mq); tmp.u[5] = qint(v1.y, mq);
            tmp.u[6] = qint(v1.z, mq); tmp.u[7] = qint(v1.w, mq);
            bq[c] = tmp.v;
        }
    }

    f32x4 oacc[4];
    #pragma unroll
    for (int i = 0; i < 4; i++) oacc[i] = (f32x4){0.f, 0.f, 0.f, 0.f};
    float mrun = -INFINITY, lrun = 0.0f;

    // cooperative staging indices: thread t loads row r = t>>2, 32B segment (t&3)
    const int sr = t >> 2;
    const int sc = (t & 3) << 4;            // ushort offset 0,16,32,48
    const unsigned short* kstage = Ki + baseQ + (size_t)sr * DMODEL + sc;
    const unsigned short* vstage = Vti + (size_t)bh * 64 * SEQ + (size_t)sr * SEQ + sc;

    for (int k0 = 0; k0 < SEQ; k0 += 64) {
        __syncthreads();   // protect LDS reuse from previous iteration
        *(short8*)&Ks[sr * 72 + sc]     = *(const short8*)(kstage + (size_t)k0 * DMODEL);
        *(short8*)&Ks[sr * 72 + sc + 8] = *(const short8*)(kstage + (size_t)k0 * DMODEL + 8);
        *(short8*)&Vt[sr * 72 + sc]     = *(const short8*)(vstage + k0);
        *(short8*)&Vt[sr * 72 + sc + 8] = *(const short8*)(vstage + k0 + 8);
        __syncthreads();

        // ---- S^T tile: A=K rows (kk), B=Q. sacc[tau][r] = S^T[k0+tau*16+qd*4+r][qg]
        f32x4 sacc[4];
        #pragma unroll
        for (int tau = 0; tau < 4; tau++) {
            short8 a0 = *(const short8*)&Ks[(tau * 16 + ml) * 72 + qd * 8];
            short8 a1 = *(const short8*)&Ks[(tau * 16 + ml) * 72 + 32 + qd * 8];
            f32x4 z4 = (f32x4){0.f, 0.f, 0.f, 0.f};
            z4 = __builtin_amdgcn_mfma_f32_16x16x32_bf16(a0, bq[0], z4, 0, 0, 0);
            sacc[tau] = __builtin_amdgcn_mfma_f32_16x16x32_bf16(a1, bq[1], z4, 0, 0, 0);
        }

        // ---- online softmax: all 16 scores of q-col qg live in this lane
        float tmax = fmaxf(fmaxf(fmaxf(sacc[0][0], sacc[0][1]), fmaxf(sacc[0][2], sacc[0][3])),
                           fmaxf(fmaxf(sacc[1][0], sacc[1][1]), fmaxf(sacc[1][2], sacc[1][3])));
        tmax = fmaxf(tmax, fmaxf(fmaxf(fmaxf(sacc[2][0], sacc[2][1]), fmaxf(sacc[2][2], sacc[2][3])),
                                 fmaxf(fmaxf(sacc[3][0], sacc[3][1]), fmaxf(sacc[3][2], sacc[3][3]))));
        tmax = fmaxf(tmax, __shfl_xor(tmax, 16));
        tmax = fmaxf(tmax, __shfl_xor(tmax, 32));
        const float mnew = fmaxf(mrun, tmax);
        const float alpha = EXP2((mrun - mnew) * c2);
        const float mc = mnew * c2;
        float p[4][4];
        float ls = 0.0f;
        #pragma unroll
        for (int tau = 0; tau < 4; tau++)
            #pragma unroll
            for (int r = 0; r < 4; r++) {
                float pv = EXP2(sacc[tau][r] * c2 - mc);
                p[tau][r] = pv;
                ls += pv;
            }
        ls += __shfl_xor(ls, 16);
        ls += __shfl_xor(ls, 32);
        lrun = lrun * alpha + ls;
        mrun = mnew;

        // ---- split P into bf16 hi/lo: p[tau][0..3] is ALREADY the K=16 B-frag
        short4v phi[4], plo[4];
        #pragma unroll
        for (int tau = 0; tau < 4; tau++) {
            U4 hh, ll;
            #pragma unroll
            for (int r = 0; r < 4; r++) {
                unsigned int u = __float_as_uint(p[tau][r]);
                unsigned int uh = (u + 0x8000u) & 0xFFFF0000u;   // round-to-nearest hi
                hh.u[r] = (unsigned short)(uh >> 16);
                float lf = p[tau][r] - __uint_as_float(uh);      // exact residual
                ll.u[r] = (unsigned short)(__float_as_uint(lf) >> 16);  // trunc lo
            }
            phi[tau] = hh.v;
            plo[tau] = ll.v;
        }

        // ---- rescale O
        #pragma unroll
        for (int i = 0; i < 4; i++) {
            oacc[i][0] *= alpha; oacc[i][1] *= alpha;
            oacc[i][2] *= alpha; oacc[i][3] *= alpha;
        }

        // ---- O^T += V^T P^T via K=16 MFMA (A = V^T 8B frags from LDS)
        #pragma unroll
        for (int td = 0; td < 4; td++) {
            #pragma unroll
            for (int tau = 0; tau < 4; tau++) {
                short4v av = *(const short4v*)&Vt[(td * 16 + ml) * 72 + tau * 16 + qd * 4];
                oacc[td] = __builtin_amdgcn_mfma_f32_16x16x16bf16_1k(av, phi[tau], oacc[td], 0, 0, 0);
                oacc[td] = __builtin_amdgcn_mfma_f32_16x16x16bf16_1k(av, plo[tau], oacc[td], 0, 0, 0);
            }
        }
    }

    // ---- epilogue: O[qg][d] = oacc[td][r] * (mv/128) / lrun
    const float inv = (mv * 0.0078125f) / lrun;
    float lmax = 0.0f;
    #pragma unroll
    for (int td = 0; td < 4; td++) {
        float4 o;
        o.x = oacc[td][0] * inv;
        o.y = oacc[td][1] * inv;
        o.z = oacc[td][2] * inv;
        o.w = oacc[td][3] * inv;
        lmax = fmaxf(lmax, fmaxf(fmaxf(fabsf(o.x), fabsf(o.y)), fmaxf(fabsf(o.z), fabsf(o.w))));
        *(float4*)&Out[baseQ + (size_t)qg * DMODEL + td * 16 + qd * 4] = o;
    }
    block_max_atomic(lmax, red, moSlot);
}

// ---------- launcher ----------
extern "C" void kernel_launch(void* const* d_in, const int* in_sizes, int n_in,
                              void* d_out, int out_size, void* d_ws, size_t ws_size,
                              hipStream_t stream) {
    const float* x  = (const float*)d_in[0];
    const float* Wq = (const float*)d_in[1];
    const float* bq = (const float*)d_in[2];
    const float* Wk = (const float*)d_in[3];
    const float* bk = (const float*)d_in[4];
    const float* Wv = (const float*)d_in[5];
    const float* bv = (const float*)d_in[6];
    const float* Wo = (const float*)d_in[7];
    const float* bo = (const float*)d_in[8];
    float* out = (float*)d_out;

    const size_t MB = 1024 * 1024;
    unsigned int* slots = (unsigned int*)d_ws;
    char* p = (char*)d_ws + 256;
    unsigned short* WqH = (unsigned short*)(p + 0 * MB);
    unsigned short* WqL = (unsigned short*)(p + 2 * MB);
    unsigned short* WkH = (unsigned short*)(p + 4 * MB);
    unsigned short* WkL = (unsigned short*)(p + 6 * MB);
    unsigned short* WvH = (unsigned short*)(p + 8 * MB);
    unsigned short* WvL = (unsigned short*)(p + 10 * MB);
    unsigned short* WoH = (unsigned short*)(p + 12 * MB);
    unsigned short* WoL = (unsigned short*)(p + 14 * MB);
    unsigned short* Xi  = (unsigned short*)(p + 16 * MB);  // 8 MB, x as int-bf16
    float* RA  = (float*)(p + 24 * MB);                    // 16 MB: Kraw -> Qraw -> Oi
    float* RB  = (float*)(p + 40 * MB);                    // 16 MB: Vraw -> attn-out raw
    unsigned short* Vti = (unsigned short*)(p + 56 * MB);  // 8 MB, V^T int-bf16
    unsigned short* Ki  = (unsigned short*)(p + 4 * MB);   // 8 MB, overlays Wk/Wv splits (dead)
    unsigned short* Oi  = (unsigned short*)RA;             // 8 MB, overlays Qraw (dead)

    hipMemsetAsync(d_ws, 0, 256, stream);  // zero max slots

    wsplit_kernel<<<dim3(1024, 4), 256, 0, stream>>>(Wq, Wk, Wv, Wo,
        WqH, WqL, WkH, WkL, WvH, WvL, WoH, WoL);
    absmax_kernel<<<1024, 256, 0, stream>>>(x, N4, slots + 0);
    quant_int_kernel<<<1024, 256, 0, stream>>>(x, Xi, slots + 0, N4);

    // K and V projections (z=0: K, z=1: V); raw fp32 out + global max
    gemm_mfma<128><<<dim3(8, 32, 2), 256, 0, stream>>>(Xi, slots + 0,
        WkH, WkL, bk, RA, slots + 2,
        WvH, WvL, bv, RB, slots + 3);
    quant_int_kernel<<<1024, 256, 0, stream>>>(RA, Ki, slots + 2, N4);
    vtrans_quant<<<dim3(32, 32), 256, 0, stream>>>(RB, Vti, slots + 3);

    // Q projection (raw into RA, over dead Kraw) — BN=64: 512 blocks, 2 WG/CU
    gemm_mfma<64><<<dim3(16, 32, 1), 256, 0, stream>>>(Xi, slots + 0,
        WqH, WqL, bq, RA, slots + 1,
        WqH, WqL, bq, RA, slots + 1);

    // attention: raw out into RB (over dead Vraw), slot4 = max|attn out|
    attn_mfma<<<dim3(32, 32), 256, 0, stream>>>(RA, Ki, Vti, slots, RB, slots + 4);
    quant_int_kernel<<<1024, 256, 0, stream>>>(RB, Oi, slots + 4, N4);

    // O projection straight into d_out (raw), then final fake-quant in place
    gemm_mfma<64><<<dim3(16, 32, 1), 256, 0, stream>>>(Oi, slots + 4,
        WoH, WoL, bo, out, slots + 5,
        WoH, WoL, bo, out, slots + 5);
    quant_out_kernel<<<1024, 256, 0, stream>>>(out, slots + 5, N4);
}

// Round 8
// 331.175 us; speedup vs baseline: 1.8918x; 1.0300x over previous
//
#include <hip/hip_runtime.h>
#include <math.h>

#define DMODEL 1024
#define SEQ    2048
#define NELEM  4194304   // B*S*d
#define N4     (NELEM / 4)

typedef __attribute__((ext_vector_type(8))) short short8;    // 8 bf16 (4 VGPRs)
typedef __attribute__((ext_vector_type(4))) short short4v;   // 4 bf16 (2 VGPRs)
typedef __attribute__((ext_vector_type(4))) float f32x4;     // C/D frag

#if __has_builtin(__builtin_amdgcn_exp2f)
#define EXP2(x) __builtin_amdgcn_exp2f(x)   // raw v_exp_f32, <=2 ulp
#else
#define EXP2(x) exp2f(x)
#endif

// async 16B global->LDS (DMA): LDS dest = wave-uniform base + lane*16
__device__ __forceinline__ void gl2lds16(const unsigned short* g, unsigned short* l) {
    __builtin_amdgcn_global_load_lds(
        (const __attribute__((address_space(1))) unsigned int*)g,
        (__attribute__((address_space(3))) unsigned int*)l,
        16, 0, 0);
}

// ---------- numeric helpers (bit-exact vs numpy reference) ----------
__device__ __forceinline__ float fq(float x, float m) {
    float t = x / m * 128.0f;      // correctly-rounded div, exact *128
    float r = rintf(t);            // half-even == np.round
    float q = r * 0.0078125f * m;
    return (m > 0.0f) ? q : x;
}
__device__ __forceinline__ unsigned short f2bf(float f) {   // RNE float->bf16 bits
    unsigned int u = __float_as_uint(f);
    u += 0x7FFFu + ((u >> 16) & 1u);
    return (unsigned short)(u >> 16);
}
__device__ __forceinline__ float bf2f(unsigned short h) {
    return __uint_as_float(((unsigned int)h) << 16);
}
// bf16 bits of rintf(x/m*128): integer in [-128,128] -> exact (truncate works)
__device__ __forceinline__ unsigned short qint(float x, float m) {
    float i = rintf(x / m * 128.0f);
    return (unsigned short)(__float_as_uint(i) >> 16);
}

__device__ __forceinline__ void block_max_atomic(float v, float* red, unsigned int* slot) {
    const int t = threadIdx.x;
    red[t] = v;
    __syncthreads();
    #pragma unroll
    for (int s = 128; s > 0; s >>= 1) {
        if (t < s) red[t] = fmaxf(red[t], red[t + s]);
        __syncthreads();
    }
    if (t == 0) atomicMax(slot, __float_as_uint(red[0]));   // bits monotone for >=0
}

// ---------- elementwise kernels ----------
__global__ __launch_bounds__(256) void absmax_kernel(const float* __restrict__ x, int n4,
                                                     unsigned int* __restrict__ slot) {
    __shared__ float red[256];
    float m = 0.0f;
    const float4* x4 = (const float4*)x;
    for (int i = blockIdx.x * 256 + threadIdx.x; i < n4; i += gridDim.x * 256) {
        float4 v = x4[i];
        m = fmaxf(m, fmaxf(fmaxf(fabsf(v.x), fabsf(v.y)), fmaxf(fabsf(v.z), fabsf(v.w))));
    }
    block_max_atomic(m, red, slot);
}

__global__ __launch_bounds__(256) void quant_int_kernel(const float* __restrict__ src,
                                                        unsigned short* __restrict__ dst,
                                                        const unsigned int* __restrict__ slot,
                                                        int n4) {
    const float m = __uint_as_float(*slot);
    const float4* s4 = (const float4*)src;
    for (int i = blockIdx.x * 256 + threadIdx.x; i < n4; i += gridDim.x * 256) {
        float4 v = s4[i];
        ushort4 o;
        o.x = qint(v.x, m); o.y = qint(v.y, m); o.z = qint(v.z, m); o.w = qint(v.w, m);
        ((ushort4*)dst)[i] = o;
    }
}

__global__ __launch_bounds__(256) void quant_out_kernel(float* __restrict__ Y,
                                                        const unsigned int* __restrict__ slot,
                                                        int n4) {
    const float m = __uint_as_float(*slot);
    float4* y4 = (float4*)Y;
    for (int i = blockIdx.x * 256 + threadIdx.x; i < n4; i += gridDim.x * 256) {
        float4 v = y4[i];
        v.x = fq(v.x, m); v.y = fq(v.y, m); v.z = fq(v.z, m); v.w = fq(v.w, m);
        y4[i] = v;
    }
}

// Split 4 weight matrices into bf16 hi+lo (W ~= hi+lo, residual ~2^-18 rel)
__global__ __launch_bounds__(256) void wsplit_kernel(
    const float* __restrict__ W0, const float* __restrict__ W1,
    const float* __restrict__ W2, const float* __restrict__ W3,
    unsigned short* __restrict__ H0, unsigned short* __restrict__ L0,
    unsigned short* __restrict__ H1, unsigned short* __restrict__ L1,
    unsigned short* __restrict__ H2, unsigned short* __restrict__ L2,
    unsigned short* __restrict__ H3, unsigned short* __restrict__ L3) {
    const int z = blockIdx.y;
    const float* W = (z == 0) ? W0 : (z == 1) ? W1 : (z == 2) ? W2 : W3;
    unsigned short* H = (z == 0) ? H0 : (z == 1) ? H1 : (z == 2) ? H2 : H3;
    unsigned short* L = (z == 0) ? L0 : (z == 1) ? L1 : (z == 2) ? L2 : L3;
    const int i = blockIdx.x * 256 + threadIdx.x;   // grid.x*256 == 1024*1024/4
    float4 w = ((const float4*)W)[i];
    ushort4 h, l;
    h.x = f2bf(w.x); l.x = f2bf(w.x - bf2f(h.x));
    h.y = f2bf(w.y); l.y = f2bf(w.y - bf2f(h.y));
    h.z = f2bf(w.z); l.z = f2bf(w.z - bf2f(h.z));
    h.w = f2bf(w.w); l.w = f2bf(w.w - bf2f(h.w));
    ((ushort4*)H)[i] = h;
    ((ushort4*)L)[i] = l;
}

// V: [b][s][1024] fp32 raw -> Vti [bh][64 d][2048 s] bf16-int (transposed for PV A-frags)
__global__ __launch_bounds__(256) void vtrans_quant(const float* __restrict__ Vraw,
                                                    unsigned short* __restrict__ Vti,
                                                    const unsigned int* __restrict__ slot) {
    __shared__ float tile[64][65];
    const float mv = __uint_as_float(*slot);
    const int t = threadIdx.x;
    const int s0 = blockIdx.x << 6;
    const int bh = blockIdx.y;
    const int b = bh >> 4, h = bh & 15;
    const int rr = t >> 4;            // 0..15
    const int cc = (t & 15) << 2;     // 0..60
    #pragma unroll
    for (int rep = 0; rep < 4; rep++) {
        int srow = rep * 16 + rr;
        float4 v = *(const float4*)&Vraw[(size_t)b * SEQ * DMODEL + (size_t)(s0 + srow) * DMODEL + h * 64 + cc];
        tile[srow][cc + 0] = v.x; tile[srow][cc + 1] = v.y;
        tile[srow][cc + 2] = v.z; tile[srow][cc + 3] = v.w;
    }
    __syncthreads();
    #pragma unroll
    for (int rep = 0; rep < 4; rep++) {
        int drow = rep * 16 + rr;
        ushort4 o;
        o.x = qint(tile[cc + 0][drow], mv);
        o.y = qint(tile[cc + 1][drow], mv);
        o.z = qint(tile[cc + 2][drow], mv);
        o.w = qint(tile[cc + 3][drow], mv);
        *(ushort4*)&Vti[(size_t)bh * 64 * SEQ + (size_t)drow * SEQ + s0 + cc] = o;
    }
}

// ---------- MFMA GEMM: y = (mA/128) * (iA @ (Whi+Wlo)^T) + b ----------
// BM=128, BN in {64,128}, BK=32. 4 waves as 2x2. m97 recipe: global_load_lds
// width=16 into UNPADDED row-major LDS, ds_read_b128 frags at 64B row stride.
// 3-way z-select so Q,K,V run in ONE dispatch (768 WGs = 3 WG/CU at BN=128).
template<int BN>
__global__ __launch_bounds__(256) void gemm_mfma(
    const unsigned short* __restrict__ Ai, const unsigned int* __restrict__ mSlot,
    const unsigned short* __restrict__ Wh0, const unsigned short* __restrict__ Wl0,
    const float* __restrict__ b0, float* __restrict__ O0, unsigned int* __restrict__ s0,
    const unsigned short* __restrict__ Wh1, const unsigned short* __restrict__ Wl1,
    const float* __restrict__ b1, float* __restrict__ O1, unsigned int* __restrict__ s1,
    const unsigned short* __restrict__ Wh2, const unsigned short* __restrict__ Wl2,
    const float* __restrict__ b2, float* __restrict__ O2, unsigned int* __restrict__ s2) {
    constexpr int NI = BN / 32;
    __shared__ __align__(16) unsigned short As[128 * 32];
    __shared__ __align__(16) unsigned short Bh[BN * 32];
    __shared__ __align__(16) unsigned short Bl[BN * 32];
    __shared__ float red[256];

    const int z = blockIdx.z;
    const unsigned short* Wh = (z == 0) ? Wh0 : (z == 1) ? Wh1 : Wh2;
    const unsigned short* Wl = (z == 0) ? Wl0 : (z == 1) ? Wl1 : Wl2;
    const float* bias = (z == 0) ? b0 : (z == 1) ? b1 : b2;
    float* O = (z == 0) ? O0 : (z == 1) ? O1 : O2;
    unsigned int* slotOut = (z == 0) ? s0 : (z == 1) ? s1 : s2;

    const float mA = __uint_as_float(*mSlot);
    const int t = threadIdx.x;
    const int lane = t & 63, w = t >> 6;
    const int ml = lane & 15, qd = lane >> 4;
    const int wm = w & 1, wn = w >> 1;
    const int m0 = blockIdx.y << 7;
    const int n0 = blockIdx.x * BN;

    const int lr = lane >> 2;           // 0..15
    const int lc = (lane & 3) << 3;     // ushort col 0,8,16,24
    const unsigned short* Asrc = Ai + (size_t)(m0 + w * 32 + lr) * DMODEL + lc;
    const unsigned short* Hsrc = Wh + (size_t)(n0 + w * (BN / 4) + lr) * DMODEL + lc;
    const unsigned short* Lsrc = Wl + (size_t)(n0 + w * (BN / 4) + lr) * DMODEL + lc;
    unsigned short* Adst = &As[(w * 32) * 32];
    unsigned short* Hdst = &Bh[(w * (BN / 4)) * 32];
    unsigned short* Ldst = &Bl[(w * (BN / 4)) * 32];

    f32x4 acc[4][NI];
    #pragma unroll
    for (int mi = 0; mi < 4; mi++)
        #pragma unroll
        for (int ni = 0; ni < NI; ni++) acc[mi][ni] = (f32x4){0.f, 0.f, 0.f, 0.f};

    for (int k0 = 0; k0 < DMODEL; k0 += 32) {
        __syncthreads();                 // previous iter's LDS reads done
        gl2lds16(Asrc + k0,               Adst);
        gl2lds16(Asrc + k0 + 16 * DMODEL, Adst + 16 * 32);
        if constexpr (BN == 128) {
            gl2lds16(Hsrc + k0,               Hdst);
            gl2lds16(Hsrc + k0 + 16 * DMODEL, Hdst + 16 * 32);
            gl2lds16(Lsrc + k0,               Ldst);
            gl2lds16(Lsrc + k0 + 16 * DMODEL, Ldst + 16 * 32);
        } else {
            gl2lds16(Hsrc + k0, Hdst);
            gl2lds16(Lsrc + k0, Ldst);
        }
        __syncthreads();                 // barrier drains vmcnt -> LDS visible

        short8 af[4];
        #pragma unroll
        for (int mi = 0; mi < 4; mi++)
            af[mi] = *(const short8*)&As[(wm * 64 + mi * 16 + ml) * 32 + qd * 8];
        #pragma unroll
        for (int ni = 0; ni < NI; ni++) {
            short8 bh = *(const short8*)&Bh[(wn * (BN / 2) + ni * 16 + ml) * 32 + qd * 8];
            short8 bl = *(const short8*)&Bl[(wn * (BN / 2) + ni * 16 + ml) * 32 + qd * 8];
            #pragma unroll
            for (int mi = 0; mi < 4; mi++) {
                acc[mi][ni] = __builtin_amdgcn_mfma_f32_16x16x32_bf16(af[mi], bh, acc[mi][ni], 0, 0, 0);
                acc[mi][ni] = __builtin_amdgcn_mfma_f32_16x16x32_bf16(af[mi], bl, acc[mi][ni], 0, 0, 0);
            }
        }
    }

    const float s = mA * 0.0078125f;
    float lmax = 0.0f;
    #pragma unroll
    for (int ni = 0; ni < NI; ni++) {
        const int col = n0 + wn * (BN / 2) + ni * 16 + ml;
        const float bc = bias[col];
        #pragma unroll
        for (int mi = 0; mi < 4; mi++) {
            #pragma unroll
            for (int r = 0; r < 4; r++) {
                int row = m0 + wm * 64 + mi * 16 + qd * 4 + r;
                float v = acc[mi][ni][r] * s + bc;
                lmax = fmaxf(lmax, fabsf(v));
                O[row * DMODEL + col] = v;
            }
        }
    }
    block_max_atomic(lmax, red, slotOut);
}

// ---------- MFMA flash attention: transposed S^T = K Q^T, double-buffered LDS ----------
// WG = 4 waves; wave w owns q-cols [q0+w*16, q0+w*16+16). Per iter: prefetch next
// K/V tile global->VGPR at top, compute current tile, ds_write into the other
// buffer, ONE barrier. S^T C-layout puts all 16 scores of one q-col in-lane ->
// in-lane softmax; P^T is ALREADY the K=16 B-operand layout -> PV shuffle-free.
__global__ __launch_bounds__(256) void attn_mfma(
    const float* __restrict__ Qraw, const unsigned short* __restrict__ Ki,
    const unsigned short* __restrict__ Vti, const unsigned int* __restrict__ slots,
    float* __restrict__ Out, unsigned int* __restrict__ moSlot) {
    __shared__ __align__(16) unsigned short Ks[2][64 * 72];   // [k][d], 2x9 KB
    __shared__ __align__(16) unsigned short Vt[2][64 * 72];   // [d][k], 2x9 KB
    __shared__ float red[256];
    union U8 { short8 v; unsigned short u[8]; };
    union U4 { short4v v; unsigned short u[4]; };

    const int t = threadIdx.x;
    const int lane = t & 63, w = t >> 6;
    const int ml = lane & 15, qd = lane >> 4;
    const int q0 = blockIdx.x << 6;
    const int bh = blockIdx.y;
    const int b = bh >> 4, h = bh & 15;
    const float mq = __uint_as_float(slots[1]);
    const float mk = __uint_as_float(slots[2]);
    const float mv = __uint_as_float(slots[3]);
    const float c2 = (mq * 0.0078125f) * (mk * 0.0078125f) * 0.125f * 1.4426950408889634f;
    const int baseQ = b * SEQ * DMODEL + h * 64;
    const int qg = q0 + w * 16 + ml;

    // Q B-frags (quantize once from raw): bq[c] holds Q[qg][c*32 + qd*8 + j]
    short8 bq[2];
    {
        const float* src = Qraw + baseQ + qg * DMODEL + qd * 8;
        #pragma unroll
        for (int c = 0; c < 2; c++) {
            float4 v0 = *(const float4*)(src + c * 32);
            float4 v1 = *(const float4*)(src + c * 32 + 4);
            U8 tmp;
            tmp.u[0] = qint(v0.x, mq); tmp.u[1] = qint(v0.y, mq);
            tmp.u[2] = qint(v0.z, mq); tmp.u[3] = qint(v0.w, mq);
            tmp.u[4] = qint(v1.x, mq); tmp.u[5] = qint(v1.y, mq);
            tmp.u[6] = qint(v1.z, mq); tmp.u[7] = qint(v1.w, mq);
            bq[c] = tmp.v;
        }
    }

    f32x4 oacc[4];
    #pragma unroll
    for (int i = 0; i < 4; i++) oacc[i] = (f32x4){0.f, 0.f, 0.f, 0.f};
    float mrun = -INFINITY, lrun = 0.0f;

    // cooperative staging: thread t handles row sr = t>>2, 32B segment (t&3)
    const int sr = t >> 2;
    const int sc = (t & 3) << 4;            // ushort offset 0,16,32,48
    const unsigned short* kstage = Ki + baseQ + (size_t)sr * DMODEL + sc;
    const unsigned short* vstage = Vti + (size_t)bh * 64 * SEQ + (size_t)sr * SEQ + sc;

    // prologue: stage tile 0 into buffer 0
    {
        short8 a = *(const short8*)kstage;
        short8 bb = *(const short8*)(kstage + 8);
        short8 c = *(const short8*)vstage;
        short8 d = *(const short8*)(vstage + 8);
        *(short8*)&Ks[0][sr * 72 + sc] = a;
        *(short8*)&Ks[0][sr * 72 + sc + 8] = bb;
        *(short8*)&Vt[0][sr * 72 + sc] = c;
        *(short8*)&Vt[0][sr * 72 + sc + 8] = d;
    }
    __syncthreads();

    for (int it = 0; it < 32; it++) {
        const int cur = it & 1;
        // ---- prefetch next tile to registers (latency hidden under compute)
        short8 nk0, nk1, nv0, nv1;
        if (it < 31) {
            const size_t ko = (size_t)(it + 1) * 64;
            nk0 = *(const short8*)(kstage + ko * DMODEL);
            nk1 = *(const short8*)(kstage + ko * DMODEL + 8);
            nv0 = *(const short8*)(vstage + ko);
            nv1 = *(const short8*)(vstage + ko + 8);
        }

        // ---- S^T tile: sacc[tau][r] = S^T[it*64+tau*16+qd*4+r][qg]
        f32x4 sacc[4];
        #pragma unroll
        for (int tau = 0; tau < 4; tau++) {
            short8 a0 = *(const short8*)&Ks[cur][(tau * 16 + ml) * 72 + qd * 8];
            short8 a1 = *(const short8*)&Ks[cur][(tau * 16 + ml) * 72 + 32 + qd * 8];
            f32x4 z4 = (f32x4){0.f, 0.f, 0.f, 0.f};
            z4 = __builtin_amdgcn_mfma_f32_16x16x32_bf16(a0, bq[0], z4, 0, 0, 0);
            sacc[tau] = __builtin_amdgcn_mfma_f32_16x16x32_bf16(a1, bq[1], z4, 0, 0, 0);
        }

        // ---- online softmax (all 16 scores of q-col qg in-lane)
        float tmax = fmaxf(fmaxf(fmaxf(sacc[0][0], sacc[0][1]), fmaxf(sacc[0][2], sacc[0][3])),
                           fmaxf(fmaxf(sacc[1][0], sacc[1][1]), fmaxf(sacc[1][2], sacc[1][3])));
        tmax = fmaxf(tmax, fmaxf(fmaxf(fmaxf(sacc[2][0], sacc[2][1]), fmaxf(sacc[2][2], sacc[2][3])),
                                 fmaxf(fmaxf(sacc[3][0], sacc[3][1]), fmaxf(sacc[3][2], sacc[3][3]))));
        tmax = fmaxf(tmax, __shfl_xor(tmax, 16));
        tmax = fmaxf(tmax, __shfl_xor(tmax, 32));
        const float mnew = fmaxf(mrun, tmax);
        const float alpha = EXP2((mrun - mnew) * c2);
        const float mc = mnew * c2;
        float p[4][4];
        float ls = 0.0f;
        #pragma unroll
        for (int tau = 0; tau < 4; tau++)
            #pragma unroll
            for (int r = 0; r < 4; r++) {
                float pv = EXP2(sacc[tau][r] * c2 - mc);
                p[tau][r] = pv;
                ls += pv;
            }
        ls += __shfl_xor(ls, 16);
        ls += __shfl_xor(ls, 32);
        lrun = lrun * alpha + ls;
        mrun = mnew;

        // ---- split P into bf16 hi/lo: p[tau][0..3] is ALREADY the K=16 B-frag
        short4v phi[4], plo[4];
        #pragma unroll
        for (int tau = 0; tau < 4; tau++) {
            U4 hh, ll;
            #pragma unroll
            for (int r = 0; r < 4; r++) {
                unsigned int u = __float_as_uint(p[tau][r]);
                unsigned int uh = (u + 0x8000u) & 0xFFFF0000u;   // round-to-nearest hi
                hh.u[r] = (unsigned short)(uh >> 16);
                float lf = p[tau][r] - __uint_as_float(uh);      // exact residual
                ll.u[r] = (unsigned short)(__float_as_uint(lf) >> 16);  // trunc lo
            }
            phi[tau] = hh.v;
            plo[tau] = ll.v;
        }

        // ---- rescale O
        #pragma unroll
        for (int i = 0; i < 4; i++) {
            oacc[i][0] *= alpha; oacc[i][1] *= alpha;
            oacc[i][2] *= alpha; oacc[i][3] *= alpha;
        }

        // ---- O^T += V^T P^T via K=16 MFMA (A = V^T 8B frags from LDS)
        #pragma unroll
        for (int td = 0; td < 4; td++) {
            #pragma unroll
            for (int tau = 0; tau < 4; tau++) {
                short4v av = *(const short4v*)&Vt[cur][(td * 16 + ml) * 72 + tau * 16 + qd * 4];
                oacc[td] = __builtin_amdgcn_mfma_f32_16x16x16bf16_1k(av, phi[tau], oacc[td], 0, 0, 0);
                oacc[td] = __builtin_amdgcn_mfma_f32_16x16x16bf16_1k(av, plo[tau], oacc[td], 0, 0, 0);
            }
        }

        // ---- write next tile into the other buffer; one barrier per iter
        if (it < 31) {
            *(short8*)&Ks[cur ^ 1][sr * 72 + sc] = nk0;
            *(short8*)&Ks[cur ^ 1][sr * 72 + sc + 8] = nk1;
            *(short8*)&Vt[cur ^ 1][sr * 72 + sc] = nv0;
            *(short8*)&Vt[cur ^ 1][sr * 72 + sc + 8] = nv1;
        }
        __syncthreads();
    }

    // ---- epilogue: O[qg][d] = oacc[td][r] * (mv/128) / lrun
    const float inv = (mv * 0.0078125f) / lrun;
    float lmax = 0.0f;
    #pragma unroll
    for (int td = 0; td < 4; td++) {
        float4 o;
        o.x = oacc[td][0] * inv;
        o.y = oacc[td][1] * inv;
        o.z = oacc[td][2] * inv;
        o.w = oacc[td][3] * inv;
        lmax = fmaxf(lmax, fmaxf(fmaxf(fabsf(o.x), fabsf(o.y)), fmaxf(fabsf(o.z), fabsf(o.w))));
        *(float4*)&Out[baseQ + (size_t)qg * DMODEL + td * 16 + qd * 4] = o;
    }
    block_max_atomic(lmax, red, moSlot);
}

// ---------- launcher ----------
extern "C" void kernel_launch(void* const* d_in, const int* in_sizes, int n_in,
                              void* d_out, int out_size, void* d_ws, size_t ws_size,
                              hipStream_t stream) {
    const float* x  = (const float*)d_in[0];
    const float* Wq = (const float*)d_in[1];
    const float* bq = (const float*)d_in[2];
    const float* Wk = (const float*)d_in[3];
    const float* bk = (const float*)d_in[4];
    const float* Wv = (const float*)d_in[5];
    const float* bv = (const float*)d_in[6];
    const float* Wo = (const float*)d_in[7];
    const float* bo = (const float*)d_in[8];
    float* out = (float*)d_out;

    const size_t MB = 1024 * 1024;
    unsigned int* slots = (unsigned int*)d_ws;
    char* p = (char*)d_ws + 256;
    unsigned short* WqH = (unsigned short*)(p + 0 * MB);
    unsigned short* WqL = (unsigned short*)(p + 2 * MB);
    unsigned short* WkH = (unsigned short*)(p + 4 * MB);
    unsigned short* WkL = (unsigned short*)(p + 6 * MB);
    unsigned short* WvH = (unsigned short*)(p + 8 * MB);
    unsigned short* WvL = (unsigned short*)(p + 10 * MB);
    unsigned short* WoH = (unsigned short*)(p + 12 * MB);
    unsigned short* WoL = (unsigned short*)(p + 14 * MB);
    unsigned short* Xi  = (unsigned short*)(p + 16 * MB);  // 8 MB, x as int-bf16
    float* RA  = (float*)(p + 24 * MB);                    // 16 MB: Kraw -> Oi
    float* RB  = (float*)(p + 40 * MB);                    // 16 MB: Vraw -> attn-out raw
    unsigned short* Vti = (unsigned short*)(p + 56 * MB);  // 8 MB, V^T int-bf16
    unsigned short* Ki  = (unsigned short*)(p + 4 * MB);   // 8 MB, overlays Wk/Wv splits (dead)
    unsigned short* Oi  = (unsigned short*)RA;             // 8 MB, overlays Kraw (dead)
    float* Qraw = out;   // d_out doubles as 16 MB scratch for raw Q (dead before O-GEMM)

    hipMemsetAsync(d_ws, 0, 256, stream);  // zero max slots

    wsplit_kernel<<<dim3(1024, 4), 256, 0, stream>>>(Wq, Wk, Wv, Wo,
        WqH, WqL, WkH, WkL, WvH, WvL, WoH, WoL);
    absmax_kernel<<<1024, 256, 0, stream>>>(x, N4, slots + 0);
    quant_int_kernel<<<1024, 256, 0, stream>>>(x, Xi, slots + 0, N4);

    // Fused Q/K/V projections in ONE dispatch (768 WGs = 3 WG/CU)
    gemm_mfma<128><<<dim3(8, 32, 3), 256, 0, stream>>>(Xi, slots + 0,
        WqH, WqL, bq, Qraw, slots + 1,
        WkH, WkL, bk, RA,   slots + 2,
        WvH, WvL, bv, RB,   slots + 3);
    quant_int_kernel<<<1024, 256, 0, stream>>>(RA, Ki, slots + 2, N4);
    vtrans_quant<<<dim3(32, 32), 256, 0, stream>>>(RB, Vti, slots + 3);

    // attention: raw out into RB (over dead Vraw), slot4 = max|attn out|
    attn_mfma<<<dim3(32, 32), 256, 0, stream>>>(Qraw, Ki, Vti, slots, RB, slots + 4);
    quant_int_kernel<<<1024, 256, 0, stream>>>(RB, Oi, slots + 4, N4);

    // O projection into d_out (overwrites dead Qraw), then final fake-quant in place
    gemm_mfma<64><<<dim3(16, 32, 1), 256, 0, stream>>>(Oi, slots + 4,
        WoH, WoL, bo, out, slots + 5,
        WoH, WoL, bo, out, slots + 5,
        WoH, WoL, bo, out, slots + 5);
    quant_out_kernel<<<1024, 256, 0, stream>>>(out, slots + 5, N4);
}

// Round 9
// 314.248 us; speedup vs baseline: 1.9937x; 1.0539x over previous
//
#include <hip/hip_runtime.h>
#include <math.h>

#define DMODEL 1024
#define SEQ    2048
#define NELEM  4194304   // B*S*d
#define N4     (NELEM / 4)

typedef __attribute__((ext_vector_type(8))) short short8;    // 8 bf16 (4 VGPRs)
typedef __attribute__((ext_vector_type(4))) short short4v;   // 4 bf16 (2 VGPRs)
typedef __attribute__((ext_vector_type(4))) float f32x4;     // C/D frag

#if __has_builtin(__builtin_amdgcn_exp2f)
#define EXP2(x) __builtin_amdgcn_exp2f(x)   // raw v_exp_f32, <=2 ulp
#else
#define EXP2(x) exp2f(x)
#endif

// async 16B global->LDS (DMA): LDS dest = wave-uniform base + lane*16
__device__ __forceinline__ void gl2lds16(const unsigned short* g, unsigned short* l) {
    __builtin_amdgcn_global_load_lds(
        (const __attribute__((address_space(1))) unsigned int*)g,
        (__attribute__((address_space(3))) unsigned int*)l,
        16, 0, 0);
}

// ---------- numeric helpers (bit-exact vs numpy reference) ----------
__device__ __forceinline__ float fq(float x, float m) {
    float t = x / m * 128.0f;      // correctly-rounded div, exact *128
    float r = rintf(t);            // half-even == np.round
    float q = r * 0.0078125f * m;
    return (m > 0.0f) ? q : x;
}
__device__ __forceinline__ unsigned short f2bf(float f) {   // RNE float->bf16 bits
    unsigned int u = __float_as_uint(f);
    u += 0x7FFFu + ((u >> 16) & 1u);
    return (unsigned short)(u >> 16);
}
__device__ __forceinline__ float bf2f(unsigned short h) {
    return __uint_as_float(((unsigned int)h) << 16);
}
// bf16 bits of rintf(x/m*128): integer in [-128,128] -> exact (truncate works)
__device__ __forceinline__ unsigned short qint(float x, float m) {
    float i = rintf(x / m * 128.0f);
    return (unsigned short)(__float_as_uint(i) >> 16);
}

__device__ __forceinline__ void block_max_atomic(float v, float* red, unsigned int* slot) {
    const int t = threadIdx.x;
    red[t] = v;
    __syncthreads();
    #pragma unroll
    for (int s = 128; s > 0; s >>= 1) {
        if (t < s) red[t] = fmaxf(red[t], red[t + s]);
        __syncthreads();
    }
    if (t == 0) atomicMax(slot, __float_as_uint(red[0]));   // bits monotone for >=0
}

// ---------- elementwise kernels ----------
// Fused: z=0..3 split W into bf16 hi/lo; z=4 absmax(x)
__global__ __launch_bounds__(256) void wsplit_absmax(
    const float* __restrict__ W0, const float* __restrict__ W1,
    const float* __restrict__ W2, const float* __restrict__ W3,
    unsigned short* __restrict__ H0, unsigned short* __restrict__ L0,
    unsigned short* __restrict__ H1, unsigned short* __restrict__ L1,
    unsigned short* __restrict__ H2, unsigned short* __restrict__ L2,
    unsigned short* __restrict__ H3, unsigned short* __restrict__ L3,
    const float* __restrict__ x, int n4, unsigned int* __restrict__ slot) {
    __shared__ float red[256];
    const int z = blockIdx.y;
    if (z == 4) {
        float m = 0.0f;
        const float4* x4 = (const float4*)x;
        for (int i = blockIdx.x * 256 + threadIdx.x; i < n4; i += gridDim.x * 256) {
            float4 v = x4[i];
            m = fmaxf(m, fmaxf(fmaxf(fabsf(v.x), fabsf(v.y)), fmaxf(fabsf(v.z), fabsf(v.w))));
        }
        block_max_atomic(m, red, slot);
        return;
    }
    const float* W = (z == 0) ? W0 : (z == 1) ? W1 : (z == 2) ? W2 : W3;
    unsigned short* H = (z == 0) ? H0 : (z == 1) ? H1 : (z == 2) ? H2 : H3;
    unsigned short* L = (z == 0) ? L0 : (z == 1) ? L1 : (z == 2) ? L2 : L3;
    const int i = blockIdx.x * 256 + threadIdx.x;   // grid.x*256 == 1024*1024/4
    float4 w = ((const float4*)W)[i];
    ushort4 h, l;
    h.x = f2bf(w.x); l.x = f2bf(w.x - bf2f(h.x));
    h.y = f2bf(w.y); l.y = f2bf(w.y - bf2f(h.y));
    h.z = f2bf(w.z); l.z = f2bf(w.z - bf2f(h.z));
    h.w = f2bf(w.w); l.w = f2bf(w.w - bf2f(h.w));
    ((ushort4*)H)[i] = h;
    ((ushort4*)L)[i] = l;
}

__global__ __launch_bounds__(256) void quant_int_kernel(const float* __restrict__ src,
                                                        unsigned short* __restrict__ dst,
                                                        const unsigned int* __restrict__ slot,
                                                        int n4) {
    const float m = __uint_as_float(*slot);
    const float4* s4 = (const float4*)src;
    for (int i = blockIdx.x * 256 + threadIdx.x; i < n4; i += gridDim.x * 256) {
        float4 v = s4[i];
        ushort4 o;
        o.x = qint(v.x, m); o.y = qint(v.y, m); o.z = qint(v.z, m); o.w = qint(v.w, m);
        ((ushort4*)dst)[i] = o;
    }
}

__global__ __launch_bounds__(256) void quant_out_kernel(float* __restrict__ Y,
                                                        const unsigned int* __restrict__ slot,
                                                        int n4) {
    const float m = __uint_as_float(*slot);
    float4* y4 = (float4*)Y;
    for (int i = blockIdx.x * 256 + threadIdx.x; i < n4; i += gridDim.x * 256) {
        float4 v = y4[i];
        v.x = fq(v.x, m); v.y = fq(v.y, m); v.z = fq(v.z, m); v.w = fq(v.w, m);
        y4[i] = v;
    }
}

// Fused post-QKV pass: y=0 quantize K raw->int; y=1 transpose+quantize V
__global__ __launch_bounds__(256) void quantK_vtrans(
    const float* __restrict__ Kraw, unsigned short* __restrict__ Ki,
    const unsigned int* __restrict__ slotK,
    const float* __restrict__ Vraw, unsigned short* __restrict__ Vti,
    const unsigned int* __restrict__ slotV, int n4) {
    __shared__ float tile[64][65];
    if (blockIdx.y == 0) {
        const float m = __uint_as_float(*slotK);
        const float4* s4 = (const float4*)Kraw;
        for (int i = blockIdx.x * 256 + threadIdx.x; i < n4; i += gridDim.x * 256) {
            float4 v = s4[i];
            ushort4 o;
            o.x = qint(v.x, m); o.y = qint(v.y, m); o.z = qint(v.z, m); o.w = qint(v.w, m);
            ((ushort4*)Ki)[i] = o;
        }
        return;
    }
    const float mv = __uint_as_float(*slotV);
    const int t = threadIdx.x;
    const int s0 = (blockIdx.x & 31) << 6;
    const int bh = blockIdx.x >> 5;
    const int b = bh >> 4, h = bh & 15;
    const int rr = t >> 4;            // 0..15
    const int cc = (t & 15) << 2;     // 0..60
    #pragma unroll
    for (int rep = 0; rep < 4; rep++) {
        int srow = rep * 16 + rr;
        float4 v = *(const float4*)&Vraw[(size_t)b * SEQ * DMODEL + (size_t)(s0 + srow) * DMODEL + h * 64 + cc];
        tile[srow][cc + 0] = v.x; tile[srow][cc + 1] = v.y;
        tile[srow][cc + 2] = v.z; tile[srow][cc + 3] = v.w;
    }
    __syncthreads();
    #pragma unroll
    for (int rep = 0; rep < 4; rep++) {
        int drow = rep * 16 + rr;
        ushort4 o;
        o.x = qint(tile[cc + 0][drow], mv);
        o.y = qint(tile[cc + 1][drow], mv);
        o.z = qint(tile[cc + 2][drow], mv);
        o.w = qint(tile[cc + 3][drow], mv);
        *(ushort4*)&Vti[(size_t)bh * 64 * SEQ + (size_t)drow * SEQ + s0 + cc] = o;
    }
}

// ---------- MFMA GEMM: y = (mA/128) * (iA @ (Whi+Wlo)^T) + b ----------
// BM=128, BN in {64,128}, BK=32. 4 waves as 2x2. m97 recipe: global_load_lds
// width=16 into UNPADDED row-major LDS, ds_read_b128 frags at 64B row stride.
// BN=64 for QKV: 1536 WGs = 6 WG/CU (cross-WG coverage of the barrier drain).
template<int BN>
__global__ __launch_bounds__(256) void gemm_mfma(
    const unsigned short* __restrict__ Ai, const unsigned int* __restrict__ mSlot,
    const unsigned short* __restrict__ Wh0, const unsigned short* __restrict__ Wl0,
    const float* __restrict__ b0, float* __restrict__ O0, unsigned int* __restrict__ s0,
    const unsigned short* __restrict__ Wh1, const unsigned short* __restrict__ Wl1,
    const float* __restrict__ b1, float* __restrict__ O1, unsigned int* __restrict__ s1,
    const unsigned short* __restrict__ Wh2, const unsigned short* __restrict__ Wl2,
    const float* __restrict__ b2, float* __restrict__ O2, unsigned int* __restrict__ s2) {
    constexpr int NI = BN / 32;
    __shared__ __align__(16) unsigned short As[128 * 32];
    __shared__ __align__(16) unsigned short Bh[BN * 32];
    __shared__ __align__(16) unsigned short Bl[BN * 32];
    __shared__ float red[256];

    const int z = blockIdx.z;
    const unsigned short* Wh = (z == 0) ? Wh0 : (z == 1) ? Wh1 : Wh2;
    const unsigned short* Wl = (z == 0) ? Wl0 : (z == 1) ? Wl1 : Wl2;
    const float* bias = (z == 0) ? b0 : (z == 1) ? b1 : b2;
    float* O = (z == 0) ? O0 : (z == 1) ? O1 : O2;
    unsigned int* slotOut = (z == 0) ? s0 : (z == 1) ? s1 : s2;

    const float mA = __uint_as_float(*mSlot);
    const int t = threadIdx.x;
    const int lane = t & 63, w = t >> 6;
    const int ml = lane & 15, qd = lane >> 4;
    const int wm = w & 1, wn = w >> 1;
    const int m0 = blockIdx.y << 7;
    const int n0 = blockIdx.x * BN;

    const int lr = lane >> 2;           // 0..15
    const int lc = (lane & 3) << 3;     // ushort col 0,8,16,24
    const unsigned short* Asrc = Ai + (size_t)(m0 + w * 32 + lr) * DMODEL + lc;
    const unsigned short* Hsrc = Wh + (size_t)(n0 + w * (BN / 4) + lr) * DMODEL + lc;
    const unsigned short* Lsrc = Wl + (size_t)(n0 + w * (BN / 4) + lr) * DMODEL + lc;
    unsigned short* Adst = &As[(w * 32) * 32];
    unsigned short* Hdst = &Bh[(w * (BN / 4)) * 32];
    unsigned short* Ldst = &Bl[(w * (BN / 4)) * 32];

    f32x4 acc[4][NI];
    #pragma unroll
    for (int mi = 0; mi < 4; mi++)
        #pragma unroll
        for (int ni = 0; ni < NI; ni++) acc[mi][ni] = (f32x4){0.f, 0.f, 0.f, 0.f};

    for (int k0 = 0; k0 < DMODEL; k0 += 32) {
        __syncthreads();                 // previous iter's LDS reads done
        gl2lds16(Asrc + k0,               Adst);
        gl2lds16(Asrc + k0 + 16 * DMODEL, Adst + 16 * 32);
        if constexpr (BN == 128) {
            gl2lds16(Hsrc + k0,               Hdst);
            gl2lds16(Hsrc + k0 + 16 * DMODEL, Hdst + 16 * 32);
            gl2lds16(Lsrc + k0,               Ldst);
            gl2lds16(Lsrc + k0 + 16 * DMODEL, Ldst + 16 * 32);
        } else {
            gl2lds16(Hsrc + k0, Hdst);
            gl2lds16(Lsrc + k0, Ldst);
        }
        __syncthreads();                 // barrier drains vmcnt -> LDS visible

        short8 af[4];
        #pragma unroll
        for (int mi = 0; mi < 4; mi++)
            af[mi] = *(const short8*)&As[(wm * 64 + mi * 16 + ml) * 32 + qd * 8];
        #pragma unroll
        for (int ni = 0; ni < NI; ni++) {
            short8 bh = *(const short8*)&Bh[(wn * (BN / 2) + ni * 16 + ml) * 32 + qd * 8];
            short8 bl = *(const short8*)&Bl[(wn * (BN / 2) + ni * 16 + ml) * 32 + qd * 8];
            #pragma unroll
            for (int mi = 0; mi < 4; mi++) {
                acc[mi][ni] = __builtin_amdgcn_mfma_f32_16x16x32_bf16(af[mi], bh, acc[mi][ni], 0, 0, 0);
                acc[mi][ni] = __builtin_amdgcn_mfma_f32_16x16x32_bf16(af[mi], bl, acc[mi][ni], 0, 0, 0);
            }
        }
    }

    const float s = mA * 0.0078125f;
    float lmax = 0.0f;
    #pragma unroll
    for (int ni = 0; ni < NI; ni++) {
        const int col = n0 + wn * (BN / 2) + ni * 16 + ml;
        const float bc = bias[col];
        #pragma unroll
        for (int mi = 0; mi < 4; mi++) {
            #pragma unroll
            for (int r = 0; r < 4; r++) {
                int row = m0 + wm * 64 + mi * 16 + qd * 4 + r;
                float v = acc[mi][ni][r] * s + bc;
                lmax = fmaxf(lmax, fabsf(v));
                O[row * DMODEL + col] = v;
            }
        }
    }
    block_max_atomic(lmax, red, slotOut);
}

// ---------- MFMA flash attention: transposed S^T = K Q^T, double-buffered LDS,
// TWO q-tiles per wave (wave owns 32 q-cols; K/V A-frags + staging + barriers
// shared across both tiles -> 2x MFMA work per unit of overhead, 2 independent
// softmax chains for ILP). In-lane softmax; P^T already in K=16 B-layout.
__global__ __launch_bounds__(256) void attn_mfma(
    const float* __restrict__ Qraw, const unsigned short* __restrict__ Ki,
    const unsigned short* __restrict__ Vti, const unsigned int* __restrict__ slots,
    float* __restrict__ Out, unsigned int* __restrict__ moSlot) {
    __shared__ __align__(16) unsigned short Ks[2][64 * 72];   // [k][d], 2x9 KB
    __shared__ __align__(16) unsigned short Vt[2][64 * 72];   // [d][k], 2x9 KB
    __shared__ float red[256];
    union U8 { short8 v; unsigned short u[8]; };
    union U4 { short4v v; unsigned short u[4]; };

    const int t = threadIdx.x;
    const int lane = t & 63, w = t >> 6;
    const int ml = lane & 15, qd = lane >> 4;
    const int q0 = blockIdx.x << 7;           // block covers 128 q-cols
    const int bh = blockIdx.y;
    const int b = bh >> 4, h = bh & 15;
    const float mq = __uint_as_float(slots[1]);
    const float mk = __uint_as_float(slots[2]);
    const float mv = __uint_as_float(slots[3]);
    const float c2 = (mq * 0.0078125f) * (mk * 0.0078125f) * 0.125f * 1.4426950408889634f;
    const int baseQ = b * SEQ * DMODEL + h * 64;
    const int qgA = q0 + w * 32 + ml;
    const int qgB = qgA + 16;

    // Q B-frags for both tiles (quantize once from raw)
    short8 bq[2][2];
    #pragma unroll
    for (int g = 0; g < 2; g++) {
        const float* src = Qraw + baseQ + (size_t)(g ? qgB : qgA) * DMODEL + qd * 8;
        #pragma unroll
        for (int c = 0; c < 2; c++) {
            float4 v0 = *(const float4*)(src + c * 32);
            float4 v1 = *(const float4*)(src + c * 32 + 4);
            U8 tmp;
            tmp.u[0] = qint(v0.x, mq); tmp.u[1] = qint(v0.y, mq);
            tmp.u[2] = qint(v0.z, mq); tmp.u[3] = qint(v0.w, mq);
            tmp.u[4] = qint(v1.x, mq); tmp.u[5] = qint(v1.y, mq);
            tmp.u[6] = qint(v1.z, mq); tmp.u[7] = qint(v1.w, mq);
            bq[g][c] = tmp.v;
        }
    }

    f32x4 oacc[2][4];
    #pragma unroll
    for (int g = 0; g < 2; g++)
        #pragma unroll
        for (int i = 0; i < 4; i++) oacc[g][i] = (f32x4){0.f, 0.f, 0.f, 0.f};
    float mrun[2] = {-INFINITY, -INFINITY}, lrun[2] = {0.f, 0.f};

    // cooperative staging: thread t handles row sr = t>>2, 32B segment (t&3)
    const int sr = t >> 2;
    const int sc = (t & 3) << 4;            // ushort offset 0,16,32,48
    const unsigned short* kstage = Ki + baseQ + (size_t)sr * DMODEL + sc;
    const unsigned short* vstage = Vti + (size_t)bh * 64 * SEQ + (size_t)sr * SEQ + sc;

    // prologue: stage tile 0 into buffer 0
    {
        short8 a = *(const short8*)kstage;
        short8 bb = *(const short8*)(kstage + 8);
        short8 c = *(const short8*)vstage;
        short8 d = *(const short8*)(vstage + 8);
        *(short8*)&Ks[0][sr * 72 + sc] = a;
        *(short8*)&Ks[0][sr * 72 + sc + 8] = bb;
        *(short8*)&Vt[0][sr * 72 + sc] = c;
        *(short8*)&Vt[0][sr * 72 + sc + 8] = d;
    }
    __syncthreads();

    for (int it = 0; it < 32; it++) {
        const int cur = it & 1;
        // ---- prefetch next tile to registers (latency hidden under compute)
        short8 nk0, nk1, nv0, nv1;
        if (it < 31) {
            const size_t ko = (size_t)(it + 1) * 64;
            nk0 = *(const short8*)(kstage + ko * DMODEL);
            nk1 = *(const short8*)(kstage + ko * DMODEL + 8);
            nv0 = *(const short8*)(vstage + ko);
            nv1 = *(const short8*)(vstage + ko + 8);
        }

        // ---- S^T tiles for both q-groups, sharing K A-frags
        f32x4 sacc[2][4];
        #pragma unroll
        for (int tau = 0; tau < 4; tau++) {
            short8 a0 = *(const short8*)&Ks[cur][(tau * 16 + ml) * 72 + qd * 8];
            short8 a1 = *(const short8*)&Ks[cur][(tau * 16 + ml) * 72 + 32 + qd * 8];
            #pragma unroll
            for (int g = 0; g < 2; g++) {
                f32x4 z4 = (f32x4){0.f, 0.f, 0.f, 0.f};
                z4 = __builtin_amdgcn_mfma_f32_16x16x32_bf16(a0, bq[g][0], z4, 0, 0, 0);
                sacc[g][tau] = __builtin_amdgcn_mfma_f32_16x16x32_bf16(a1, bq[g][1], z4, 0, 0, 0);
            }
        }

        // ---- online softmax per tile (all 16 scores of a q-col in-lane)
        float alpha[2];
        short4v phi[2][4], plo[2][4];
        #pragma unroll
        for (int g = 0; g < 2; g++) {
            float tmax = fmaxf(fmaxf(fmaxf(sacc[g][0][0], sacc[g][0][1]), fmaxf(sacc[g][0][2], sacc[g][0][3])),
                               fmaxf(fmaxf(sacc[g][1][0], sacc[g][1][1]), fmaxf(sacc[g][1][2], sacc[g][1][3])));
            tmax = fmaxf(tmax, fmaxf(fmaxf(fmaxf(sacc[g][2][0], sacc[g][2][1]), fmaxf(sacc[g][2][2], sacc[g][2][3])),
                                     fmaxf(fmaxf(sacc[g][3][0], sacc[g][3][1]), fmaxf(sacc[g][3][2], sacc[g][3][3]))));
            tmax = fmaxf(tmax, __shfl_xor(tmax, 16));
            tmax = fmaxf(tmax, __shfl_xor(tmax, 32));
            const float mnew = fmaxf(mrun[g], tmax);
            alpha[g] = EXP2((mrun[g] - mnew) * c2);
            const float mc = mnew * c2;
            float ls = 0.0f;
            #pragma unroll
            for (int tau = 0; tau < 4; tau++) {
                U4 hh, ll;
                #pragma unroll
                for (int r = 0; r < 4; r++) {
                    float pv = EXP2(sacc[g][tau][r] * c2 - mc);
                    ls += pv;
                    unsigned int u = __float_as_uint(pv);
                    unsigned int uh = (u + 0x8000u) & 0xFFFF0000u;   // RNE-ish hi
                    hh.u[r] = (unsigned short)(uh >> 16);
                    float lf = pv - __uint_as_float(uh);             // exact residual
                    ll.u[r] = (unsigned short)(__float_as_uint(lf) >> 16);  // trunc lo
                }
                phi[g][tau] = hh.v;
                plo[g][tau] = ll.v;
            }
            ls += __shfl_xor(ls, 16);
            ls += __shfl_xor(ls, 32);
            lrun[g] = lrun[g] * alpha[g] + ls;
            mrun[g] = mnew;
        }

        // ---- rescale O
        #pragma unroll
        for (int g = 0; g < 2; g++)
            #pragma unroll
            for (int i = 0; i < 4; i++) {
                oacc[g][i][0] *= alpha[g]; oacc[g][i][1] *= alpha[g];
                oacc[g][i][2] *= alpha[g]; oacc[g][i][3] *= alpha[g];
            }

        // ---- O^T += V^T P^T via K=16 MFMA; V A-frags shared across both tiles
        #pragma unroll
        for (int td = 0; td < 4; td++) {
            #pragma unroll
            for (int tau = 0; tau < 4; tau++) {
                short4v av = *(const short4v*)&Vt[cur][(td * 16 + ml) * 72 + tau * 16 + qd * 4];
                #pragma unroll
                for (int g = 0; g < 2; g++) {
                    oacc[g][td] = __builtin_amdgcn_mfma_f32_16x16x16bf16_1k(av, phi[g][tau], oacc[g][td], 0, 0, 0);
                    oacc[g][td] = __builtin_amdgcn_mfma_f32_16x16x16bf16_1k(av, plo[g][tau], oacc[g][td], 0, 0, 0);
                }
            }
        }

        // ---- write next tile into the other buffer; one barrier per iter
        if (it < 31) {
            *(short8*)&Ks[cur ^ 1][sr * 72 + sc] = nk0;
            *(short8*)&Ks[cur ^ 1][sr * 72 + sc + 8] = nk1;
            *(short8*)&Vt[cur ^ 1][sr * 72 + sc] = nv0;
            *(short8*)&Vt[cur ^ 1][sr * 72 + sc + 8] = nv1;
        }
        __syncthreads();
    }

    // ---- epilogue: O[qg][d] = oacc[td][r] * (mv/128) / lrun
    float lmax = 0.0f;
    #pragma unroll
    for (int g = 0; g < 2; g++) {
        const float inv = (mv * 0.0078125f) / lrun[g];
        const int qg = g ? qgB : qgA;
        #pragma unroll
        for (int td = 0; td < 4; td++) {
            float4 o;
            o.x = oacc[g][td][0] * inv;
            o.y = oacc[g][td][1] * inv;
            o.z = oacc[g][td][2] * inv;
            o.w = oacc[g][td][3] * inv;
            lmax = fmaxf(lmax, fmaxf(fmaxf(fabsf(o.x), fabsf(o.y)), fmaxf(fabsf(o.z), fabsf(o.w))));
            *(float4*)&Out[baseQ + (size_t)qg * DMODEL + td * 16 + qd * 4] = o;
        }
    }
    block_max_atomic(lmax, red, moSlot);
}

// ---------- launcher ----------
extern "C" void kernel_launch(void* const* d_in, const int* in_sizes, int n_in,
                              void* d_out, int out_size, void* d_ws, size_t ws_size,
                              hipStream_t stream) {
    const float* x  = (const float*)d_in[0];
    const float* Wq = (const float*)d_in[1];
    const float* bq = (const float*)d_in[2];
    const float* Wk = (const float*)d_in[3];
    const float* bk = (const float*)d_in[4];
    const float* Wv = (const float*)d_in[5];
    const float* bv = (const float*)d_in[6];
    const float* Wo = (const float*)d_in[7];
    const float* bo = (const float*)d_in[8];
    float* out = (float*)d_out;

    const size_t MB = 1024 * 1024;
    unsigned int* slots = (unsigned int*)d_ws;
    char* p = (char*)d_ws + 256;
    unsigned short* WqH = (unsigned short*)(p + 0 * MB);
    unsigned short* WqL = (unsigned short*)(p + 2 * MB);
    unsigned short* WkH = (unsigned short*)(p + 4 * MB);
    unsigned short* WkL = (unsigned short*)(p + 6 * MB);
    unsigned short* WvH = (unsigned short*)(p + 8 * MB);
    unsigned short* WvL = (unsigned short*)(p + 10 * MB);
    unsigned short* WoH = (unsigned short*)(p + 12 * MB);
    unsigned short* WoL = (unsigned short*)(p + 14 * MB);
    unsigned short* Xi  = (unsigned short*)(p + 16 * MB);  // 8 MB, x as int-bf16
    float* RA  = (float*)(p + 24 * MB);                    // 16 MB: Kraw -> Oi
    float* RB  = (float*)(p + 40 * MB);                    // 16 MB: Vraw -> attn-out raw
    unsigned short* Vti = (unsigned short*)(p + 56 * MB);  // 8 MB, V^T int-bf16
    unsigned short* Ki  = (unsigned short*)(p + 4 * MB);   // 8 MB, overlays Wk/Wv splits (dead)
    unsigned short* Oi  = (unsigned short*)RA;             // 8 MB, overlays Kraw (dead)
    float* Qraw = out;   // d_out doubles as 16 MB scratch for raw Q (dead before O-GEMM)

    hipMemsetAsync(d_ws, 0, 256, stream);  // zero max slots

    // fused weight-split (z=0..3) + absmax(x) (z=4)
    wsplit_absmax<<<dim3(1024, 5), 256, 0, stream>>>(Wq, Wk, Wv, Wo,
        WqH, WqL, WkH, WkL, WvH, WvL, WoH, WoL, x, N4, slots + 0);
    quant_int_kernel<<<1024, 256, 0, stream>>>(x, Xi, slots + 0, N4);

    // Fused Q/K/V projections in ONE dispatch; BN=64 -> 1536 WGs = 6 WG/CU
    gemm_mfma<64><<<dim3(16, 32, 3), 256, 0, stream>>>(Xi, slots + 0,
        WqH, WqL, bq, Qraw, slots + 1,
        WkH, WkL, bk, RA,   slots + 2,
        WvH, WvL, bv, RB,   slots + 3);
    // fused: quantize K (y=0) + transpose-quantize V (y=1)
    quantK_vtrans<<<dim3(1024, 2), 256, 0, stream>>>(RA, Ki, slots + 2,
                                                     RB, Vti, slots + 3, N4);

    // attention: raw out into RB (over dead Vraw), slot4 = max|attn out|
    attn_mfma<<<dim3(16, 32), 256, 0, stream>>>(Qraw, Ki, Vti, slots, RB, slots + 4);
    quant_int_kernel<<<1024, 256, 0, stream>>>(RB, Oi, slots + 4, N4);

    // O projection into d_out (overwrites dead Qraw), then final fake-quant in place
    gemm_mfma<64><<<dim3(16, 32, 1), 256, 0, stream>>>(Oi, slots + 4,
        WoH, WoL, bo, out, slots + 5,
        WoH, WoL, bo, out, slots + 5,
        WoH, WoL, bo, out, slots + 5);
    quant_out_kernel<<<1024, 256, 0, stream>>>(out, slots + 5, N4);
}